// Round 17
// baseline (483.679 us; speedup 1.0000x reference)
//
#include <hip/hip_runtime.h>
#include <hip/hip_bf16.h>
#include <cstdint>
#include <cstddef>

// Problem dims (compile-time)
constexpr int Bc = 8;
constexpr int Vc = 2048;   // S*T
constexpr int Pc = 512;
constexpr int Hc = 8;
constexpr int Lc = 2;
constexpr int ROWS_KV = Bc * Vc;   // 16384
constexpr int ROWS_AT = Bc * Pc;   // 4096

typedef __attribute__((ext_vector_type(8))) short bf16x8;   // 8 bf16 (4 VGPRs)
typedef __attribute__((ext_vector_type(4))) float f32x4;

static __device__ __forceinline__ unsigned short f2bf(float v) {
    __hip_bfloat16 h = __float2bfloat16(v);
    return *(unsigned short*)&h;
}
static __device__ __forceinline__ float bflo(unsigned int u) {
    return __uint_as_float(u << 16);
}
static __device__ __forceinline__ float bfhi(unsigned int u) {
    return __uint_as_float(u & 0xffff0000u);
}

// ---------------------------------------------------------------------------
// Prep: encoded fp32 -> bf16 (row-major [16384][256])
// ---------------------------------------------------------------------------
__global__ __launch_bounds__(256) void conv_x_kernel(
    const float* __restrict__ x, unsigned short* __restrict__ xb)
{
    const int i = blockIdx.x * 256 + threadIdx.x;   // 1 float4 per thread
    float4 v = ((const float4*)x)[i];
    ushort4 o;
    o.x = f2bf(v.x); o.y = f2bf(v.y); o.z = f2bf(v.z); o.w = f2bf(v.w);
    ((ushort4*)xb)[i] = o;
}

// ---------------------------------------------------------------------------
// Merged prep: all weight transposes [K x C] fp32 -> [C x 256] bf16.
// ---------------------------------------------------------------------------
__global__ __launch_bounds__(256) void transpose_all_kernel(
    const float* kW1, const float* vW1, const float* kW2, const float* vW2,
    const float* kW3, const float* vW3,
    const float* ds_W, const float* ff_W1, const float* ff_W2,
    const float* de_W1, const float* de_W2, const float* de_W3,
    unsigned short* __restrict__ W1t, unsigned short* __restrict__ W2t,
    unsigned short* __restrict__ W3t, unsigned short* __restrict__ Wm)
{
    const int z = blockIdx.z;
    const float* src;
    unsigned short* dst;
    int C;
    if (z < 32) {
        const int net = z;
        src = ((net >> 4) ? vW1 : kW1) + (size_t)(net & 15) * 257 * 256;
        dst = W1t + (size_t)net * 65536;
        C = 256;
    } else if (z < 64) {
        const int net = z - 32;
        src = ((net >> 4) ? vW2 : kW2) + (size_t)(net & 15) * 256 * 256;
        dst = W2t + (size_t)net * 65536;
        C = 256;
    } else if (z < 96) {
        const int net = z - 64;
        src = ((net >> 4) ? vW3 : kW3) + (size_t)(net & 15) * 256 * 32;
        dst = W3t + (size_t)net * 8192;
        C = 32;
    } else {
        const int id = z - 96;
        const float* srcs[8] = {ds_W, ff_W1, ff_W1 + (size_t)65536,
                                ff_W2, ff_W2 + (size_t)65536, de_W1, de_W2, de_W3};
        src = srcs[id];
        dst = Wm + (size_t)id * 65536;
        C = (id == 7) ? 128 : 256;
    }
    if (blockIdx.x * 32 >= C) return;
    __shared__ float t[32][33];
    const int c0 = blockIdx.x * 32, k0 = blockIdx.y * 32;
    const int tx = threadIdx.x & 31, ty = threadIdx.x >> 5;
    #pragma unroll
    for (int i = 0; i < 32; i += 8)
        t[ty + i][tx] = src[(size_t)(k0 + ty + i) * C + (c0 + tx)];
    __syncthreads();
    #pragma unroll
    for (int i = 0; i < 32; i += 8)
        dst[(size_t)(c0 + ty + i) * 256 + (k0 + tx)] = f2bf(t[tx][ty + i]);
}

// h-buf XOR swizzle: rows x 256 shorts (32 chunks of 8 shorts).
static __device__ __forceinline__ int hsw_chunk(int row, int ks, int quad) {
    int c = ks * 4 + quad;
    int p = c ^ (row & 31);
    return row * 256 + p * 8;
}
static __device__ __forceinline__ int hsw_elem(int row, int col) {
    int p = (col >> 3) ^ (row & 31);
    return row * 256 + p * 8 + (col & 7);
}

// ---------------------------------------------------------------------------
// Fused 3-layer KV MLP — v7b (best measured): weight-resident W1/W2 in
// registers, W3 in 16KB swizzled LDS, 8 waves, 512 blocks.
// Output bf16 [l][b][v][h*32].
// ---------------------------------------------------------------------------
__global__ __launch_bounds__(512, 2) void kv_mfma_kernel(
    const unsigned short* __restrict__ Xbf, const float* __restrict__ true_u,
    const unsigned short* __restrict__ W1t, const unsigned short* __restrict__ W2t,
    const unsigned short* __restrict__ W3t,
    const float* __restrict__ kW1, const float* __restrict__ vW1,
    const float* __restrict__ kb1, const float* __restrict__ kb2, const float* __restrict__ kb3,
    const float* __restrict__ vb1, const float* __restrict__ vb2, const float* __restrict__ vb3,
    unsigned short* __restrict__ keys, unsigned short* __restrict__ vals)
{
    __shared__ unsigned short hbuf[64 * 256];    // 32 KB: X -> h1 -> h2 (swizzled)
    __shared__ unsigned short w3buf[32 * 256];   // 16 KB: W3 slice (swizzled)
    __shared__ float tub[64];                    // true_u tile

    const int tid = threadIdx.x;
    const int w = tid >> 6, lane = tid & 63;
    const int ln = lane & 15, quad = lane >> 4;
    const int lh = blockIdx.y, isv = blockIdx.z;
    const int net = isv * 16 + lh;
    const float* W1f = (isv ? vW1 : kW1) + (size_t)lh * 257 * 256;
    const float* b1  = (isv ? vb1 : kb1) + lh * 256;
    const float* b2  = (isv ? vb2 : kb2) + lh * 256;
    const float* b3  = (isv ? vb3 : kb3) + lh * 32;
    const unsigned short* w1 = W1t + (size_t)net * 65536;
    const unsigned short* w2 = W2t + (size_t)net * 65536;
    const unsigned short* w3 = W3t + (size_t)net * 8192;
    unsigned short* outp = isv ? vals : keys;
    const int base = blockIdx.x * 1024;          // row-group (16 tiles)
    const int cb = w * 32;                       // wave's column base (stages 1-2)

    // ---- one-time: W1/W2 column slices -> registers ----
    bf16x8 B1[16], B2[16];
    {
        const unsigned short* p1 = w1 + (size_t)(cb + ln) * 256 + quad * 8;
        const unsigned short* p2 = w2 + (size_t)(cb + ln) * 256 + quad * 8;
        #pragma unroll
        for (int ks = 0; ks < 8; ++ks)
            #pragma unroll
            for (int ct = 0; ct < 2; ++ct) {
                B1[ks * 2 + ct] = *(const bf16x8*)(p1 + (size_t)ct * 16 * 256 + ks * 32);
                B2[ks * 2 + ct] = *(const bf16x8*)(p2 + (size_t)ct * 16 * 256 + ks * 32);
            }
    }
    // ---- one-time: W3 -> swizzled LDS ----
    {
        #pragma unroll
        for (int j = 0; j < 2; ++j) {
            const int cidx = tid * 2 + j;
            const int col = cidx >> 5, c = cidx & 31;
            uint4 d = *(const uint4*)(w3 + cidx * 8);
            *(uint4*)&w3buf[col * 256 + (c ^ (col & 31)) * 8] = d;
        }
    }
    float w1f[2], b1v[2], b2v[2];
    #pragma unroll
    for (int ct = 0; ct < 2; ++ct) {
        const int col = cb + ct * 16 + ln;
        w1f[ct] = W1f[256 * 256 + col];
        b1v[ct] = b1[col];
        b2v[ct] = b2[col];
    }
    const int rt3 = w & 3, ct3 = w >> 2;
    const float b3v = b3[ct3 * 16 + ln];

    const int b_ = base >> 11;
    const int l_ = lh >> 3, h_ = lh & 7;
    unsigned short* ob = outp + (((size_t)l_ * Bc + b_) * Vc) * 256 + h_ * 32;

    const f32x4 zero = {0.f, 0.f, 0.f, 0.f};
    const int xr = tid >> 3, cg = tid & 7;

    for (int t = 0; t < 16; ++t) {
        const int row0 = base + t * 64;
        __syncthreads();

        {
            const unsigned short* gx = Xbf + (size_t)(row0 + xr) * 256;
            #pragma unroll
            for (int j = 0; j < 4; ++j) {
                const int c = j * 8 + cg;
                uint4 d = *(const uint4*)(gx + c * 8);
                *(uint4*)&hbuf[xr * 256 + (c ^ (xr & 31)) * 8] = d;
            }
            if (tid < 64) tub[tid] = true_u[row0 + tid];
        }
        __syncthreads();

        // ---- stage 1 ----
        f32x4 acc[4][2];
        #pragma unroll
        for (int rt = 0; rt < 4; ++rt)
            #pragma unroll
            for (int ct = 0; ct < 2; ++ct) acc[rt][ct] = zero;
        #pragma unroll
        for (int ks = 0; ks < 8; ++ks) {
            bf16x8 A[4];
            #pragma unroll
            for (int rt = 0; rt < 4; ++rt)
                A[rt] = *(const bf16x8*)&hbuf[hsw_chunk(rt * 16 + ln, ks, quad)];
            #pragma unroll
            for (int rt = 0; rt < 4; ++rt)
                #pragma unroll
                for (int ct = 0; ct < 2; ++ct)
                    acc[rt][ct] = __builtin_amdgcn_mfma_f32_16x16x32_bf16(A[rt], B1[ks * 2 + ct], acc[rt][ct], 0, 0, 0);
        }
        __syncthreads();
        #pragma unroll
        for (int ct = 0; ct < 2; ++ct) {
            const int col = cb + ct * 16 + ln;
            #pragma unroll
            for (int rt = 0; rt < 4; ++rt)
                #pragma unroll
                for (int r = 0; r < 4; ++r) {
                    const int row = rt * 16 + quad * 4 + r;
                    float v = fmaxf(acc[rt][ct][r] + b1v[ct] + tub[row] * w1f[ct], 0.f);
                    hbuf[hsw_elem(row, col)] = f2bf(v);
                }
        }
        __syncthreads();

        // ---- stage 2 ----
        #pragma unroll
        for (int rt = 0; rt < 4; ++rt)
            #pragma unroll
            for (int ct = 0; ct < 2; ++ct) acc[rt][ct] = zero;
        #pragma unroll
        for (int ks = 0; ks < 8; ++ks) {
            bf16x8 A[4];
            #pragma unroll
            for (int rt = 0; rt < 4; ++rt)
                A[rt] = *(const bf16x8*)&hbuf[hsw_chunk(rt * 16 + ln, ks, quad)];
            #pragma unroll
            for (int rt = 0; rt < 4; ++rt)
                #pragma unroll
                for (int ct = 0; ct < 2; ++ct)
                    acc[rt][ct] = __builtin_amdgcn_mfma_f32_16x16x32_bf16(A[rt], B2[ks * 2 + ct], acc[rt][ct], 0, 0, 0);
        }
        __syncthreads();
        #pragma unroll
        for (int ct = 0; ct < 2; ++ct) {
            const int col = cb + ct * 16 + ln;
            #pragma unroll
            for (int rt = 0; rt < 4; ++rt)
                #pragma unroll
                for (int r = 0; r < 4; ++r) {
                    const int row = rt * 16 + quad * 4 + r;
                    hbuf[hsw_elem(row, col)] = f2bf(fmaxf(acc[rt][ct][r] + b2v[ct], 0.f));
                }
        }
        __syncthreads();

        // ---- stage 3 ----
        f32x4 acc3 = zero;
        #pragma unroll
        for (int ks = 0; ks < 8; ++ks) {
            bf16x8 A  = *(const bf16x8*)&hbuf[hsw_chunk(rt3 * 16 + ln, ks, quad)];
            bf16x8 Bv = *(const bf16x8*)&w3buf[hsw_chunk(ct3 * 16 + ln, ks, quad)];
            acc3 = __builtin_amdgcn_mfma_f32_16x16x32_bf16(A, Bv, acc3, 0, 0, 0);
        }
        #pragma unroll
        for (int r = 0; r < 4; ++r) {
            const int grow = row0 + rt3 * 16 + quad * 4 + r;
            ob[(size_t)(grow & 2047) * 256 + ct3 * 16 + ln] = f2bf(acc3[r] + b3v);
        }
    }
}

// ---------------------------------------------------------------------------
// FUSED TAIL v2: per block = 8 rows, 512 blocks (2/CU), 512 threads.
// ds GEMM -> [attn -> LN1 -> ff1 -> ff2 -> LN2] x2 -> de1 -> de2 -> de3+loss.
// GEMM tiles padded to M=16 (rows 8-15 zeroed once; pad rows never stored).
// Attention: wave w owns row w (8 heads serial, phase1+PV in-wave).
// ---------------------------------------------------------------------------
__global__ __launch_bounds__(512, 2) void decoder_kernel(
    const unsigned short* __restrict__ Xbf, const float* __restrict__ true_u,
    const unsigned short* __restrict__ keys, const unsigned short* __restrict__ vals,
    const int* __restrict__ nbr, const float* __restrict__ mask,
    const int* __restrict__ pp, const unsigned short* __restrict__ Wm,
    const float* __restrict__ ds_b,
    const float* __restrict__ ln1_g, const float* __restrict__ ln1_b,
    const float* __restrict__ ff_b1, const float* __restrict__ ff_b2,
    const float* __restrict__ ln2_g, const float* __restrict__ ln2_b,
    const float* __restrict__ de_b1, const float* __restrict__ de_b2,
    const float* __restrict__ de_b3, float* __restrict__ outp)
{
    __shared__ float avF[8][264];               // activation fp32 (residual/q)
    __shared__ float attF[8][264];              // attention output fp32
    __shared__ unsigned short abuf[16 * 256];   // activation bf16 (swizzled, padded)
    __shared__ unsigned short hbuf[16 * 256];   // GEMM intermediate (swizzled, padded)
    __shared__ int   ni_s[8][64];
    __shared__ float wtsb[8][64];
    __shared__ float psum[8][8], psq[8][8];
    __shared__ float rowmax[8];
    __shared__ int   tcol[8];
    __shared__ int   pps[8];

    const int tid = threadIdx.x;
    const int w = tid >> 6, lane = tid & 63;
    const int ln = lane & 15, quad = lane >> 4;
    const int bid = blockIdx.x;
    const int b = bid & 7;                       // XCD-affine batch
    const int r0 = b * 512 + (bid >> 3) * 8;     // global row base
    const int cb = w * 32;                       // GEMM column base

    const f32x4 zero = {0.f, 0.f, 0.f, 0.f};

    // ---- init: pp values + neighbor indices ----
    if (tid < 8) pps[tid] = pp[(r0 + tid) & 511];
    {
        const int row = tid >> 6, n = tid & 63;  // 512 = 8*64, one per thread
        ni_s[row][n] = nbr[((r0 + row) & 511) * 64 + n];
    }
    __syncthreads();

    // ---- gather X rows into abuf + zero pad rows 8-15 of abuf/hbuf ----
    if (tid < 256) {
        const int row = tid >> 5, c = tid & 31;
        const size_t arow = (size_t)b * Vc + pps[row];
        uint4 d = *(const uint4*)(Xbf + arow * 256 + c * 8);
        *(uint4*)&abuf[row * 256 + ((c ^ row) * 8)] = d;
    } else {
        const int idx = tid - 256;               // 0..255 = 2 bufs x 128 uint4
        const int buf = idx >> 7, j = idx & 127;
        const int row = 8 + (j >> 4), chunk = j & 15;
        uint4 z; z.x = 0; z.y = 0; z.z = 0; z.w = 0;
        *(uint4*)&((buf ? hbuf : abuf)[row * 256 + chunk * 16]) = z;
    }
    __syncthreads();

    // ---- ds GEMM: avF/abuf = Xg @ ds_W + ds_b ----
    {
        const unsigned short* Wt = Wm;           // slot 0
        f32x4 acc[2]; acc[0] = zero; acc[1] = zero;
        const unsigned short* wb = Wt + (size_t)(cb + ln) * 256 + quad * 8;
        #pragma unroll
        for (int ks = 0; ks < 8; ++ks) {
            bf16x8 A = *(const bf16x8*)&abuf[hsw_chunk(ln, ks, quad)];
            #pragma unroll
            for (int ct = 0; ct < 2; ++ct) {
                bf16x8 Bv = *(const bf16x8*)(wb + (size_t)ct * 16 * 256 + ks * 32);
                acc[ct] = __builtin_amdgcn_mfma_f32_16x16x32_bf16(A, Bv, acc[ct], 0, 0, 0);
            }
        }
        __syncthreads();   // all X reads done before abuf overwrite
        #pragma unroll
        for (int ct = 0; ct < 2; ++ct) {
            const int col = cb + ct * 16 + ln;
            const float bb = ds_b[col];
            #pragma unroll
            for (int r = 0; r < 4; ++r) {
                const int row = quad * 4 + r;
                if (row < 8) {
                    float v = acc[ct][r] + bb;
                    avF[row][col] = v;
                    abuf[hsw_elem(row, col)] = f2bf(v);
                }
            }
        }
    }
    __syncthreads();

    // ==================== transformer layers ====================
    for (int l = 0; l < Lc; ++l) {
        const unsigned short* kvb = keys + (((size_t)l * Bc + b) * Vc) * 256;
        const unsigned short* vvb = vals + (((size_t)l * Bc + b) * Vc) * 256;

        // ---- attention + LN1: wave w owns row w ----
        {
            const int row = w;
            const int p = (r0 + row) & 511;
            const int n = lane;
            for (int h = 0; h < 8; ++h) {
                float q[32];
                #pragma unroll
                for (int j = 0; j < 8; ++j) {
                    float4 t4 = *(const float4*)&avF[row][h * 32 + j * 4];
                    q[j * 4 + 0] = t4.x; q[j * 4 + 1] = t4.y;
                    q[j * 4 + 2] = t4.z; q[j * 4 + 3] = t4.w;
                }
                const int vi = ni_s[row][n];
                const unsigned short* kp = kvb + (size_t)vi * 256 + h * 32;
                float s = 0.f;
                #pragma unroll
                for (int j = 0; j < 4; ++j) {
                    uint4 u = *(const uint4*)(kp + j * 8);
                    s += q[j * 8 + 0] * bflo(u.x) + q[j * 8 + 1] * bfhi(u.x);
                    s += q[j * 8 + 2] * bflo(u.y) + q[j * 8 + 3] * bfhi(u.y);
                    s += q[j * 8 + 4] * bflo(u.z) + q[j * 8 + 5] * bfhi(u.z);
                    s += q[j * 8 + 6] * bflo(u.w) + q[j * 8 + 7] * bfhi(u.w);
                }
                s = (s - mask[p * 64 + n]) * 0.17677669529663689f;
                float mx = s;
                #pragma unroll
                for (int off = 32; off >= 1; off >>= 1) mx = fmaxf(mx, __shfl_xor(mx, off));
                float e = expf(s - mx);
                float sum = e;
                #pragma unroll
                for (int off = 32; off >= 1; off >>= 1) sum += __shfl_xor(sum, off);
                wtsb[w][n] = e / sum;
                const int nb4 = n >> 2, cg8 = (n & 3) * 8;
                float a[8];
                #pragma unroll
                for (int j = 0; j < 8; ++j) a[j] = 0.f;
                #pragma unroll
                for (int pass = 0; pass < 4; ++pass) {
                    const int nn = pass * 16 + nb4;
                    const float wgt = wtsb[w][nn];
                    const unsigned short* vp = vvb + (size_t)ni_s[row][nn] * 256 + h * 32 + cg8;
                    uint4 u = *(const uint4*)vp;
                    a[0] += wgt * bflo(u.x); a[1] += wgt * bfhi(u.x);
                    a[2] += wgt * bflo(u.y); a[3] += wgt * bfhi(u.y);
                    a[4] += wgt * bflo(u.z); a[5] += wgt * bfhi(u.z);
                    a[6] += wgt * bflo(u.w); a[7] += wgt * bfhi(u.w);
                }
                #pragma unroll
                for (int off = 4; off <= 32; off <<= 1)
                    #pragma unroll
                    for (int j = 0; j < 8; ++j)
                        a[j] += __shfl_xor(a[j], off);
                if (nb4 == 0)
                    #pragma unroll
                    for (int j = 0; j < 8; ++j)
                        attF[row][h * 32 + cg8 + j] = a[j];
            }
            // LN1 for this row (in-wave)
            {
                const int c0 = lane * 4;
                float x[4];
                float sl = 0.f, ql = 0.f;
                #pragma unroll
                for (int j = 0; j < 4; ++j) {
                    x[j] = avF[row][c0 + j] + attF[row][c0 + j];
                    sl += x[j]; ql += x[j] * x[j];
                }
                #pragma unroll
                for (int off = 32; off >= 1; off >>= 1) {
                    sl += __shfl_xor(sl, off);
                    ql += __shfl_xor(ql, off);
                }
                const float mu = sl * (1.0f / 256.0f);
                const float var = ql * (1.0f / 256.0f) - mu * mu;
                const float rstd = 1.0f / sqrtf(fmaxf(var, 0.f) + 1e-5f);
                #pragma unroll
                for (int j = 0; j < 4; ++j) {
                    const int col = c0 + j;
                    float o = (x[j] - mu) * rstd * ln1_g[l * 256 + col] + ln1_b[l * 256 + col];
                    avF[row][col] = o;
                    abuf[hsw_elem(row, col)] = f2bf(o);
                }
            }
        }
        __syncthreads();

        // ---- ff stage A: T1 = relu(abuf @ W1 + b1) -> hbuf ----
        {
            const unsigned short* W1 = Wm + (size_t)(1 + l) * 65536;
            f32x4 acc[2]; acc[0] = zero; acc[1] = zero;
            const unsigned short* wb = W1 + (size_t)(cb + ln) * 256 + quad * 8;
            #pragma unroll
            for (int ks = 0; ks < 8; ++ks) {
                bf16x8 A = *(const bf16x8*)&abuf[hsw_chunk(ln, ks, quad)];
                #pragma unroll
                for (int ct = 0; ct < 2; ++ct) {
                    bf16x8 Bv = *(const bf16x8*)(wb + (size_t)ct * 16 * 256 + ks * 32);
                    acc[ct] = __builtin_amdgcn_mfma_f32_16x16x32_bf16(A, Bv, acc[ct], 0, 0, 0);
                }
            }
            #pragma unroll
            for (int ct = 0; ct < 2; ++ct) {
                const int col = cb + ct * 16 + ln;
                const float bb = ff_b1[l * 256 + col];
                #pragma unroll
                for (int r = 0; r < 4; ++r) {
                    const int row = quad * 4 + r;
                    if (row < 8)
                        hbuf[hsw_elem(row, col)] = f2bf(fmaxf(acc[ct][r] + bb, 0.f));
                }
            }
        }
        __syncthreads();

        // ---- ff stage B + residual + LN2 ----
        {
            const unsigned short* W2 = Wm + (size_t)(3 + l) * 65536;
            f32x4 acc[2]; acc[0] = zero; acc[1] = zero;
            const unsigned short* wb = W2 + (size_t)(cb + ln) * 256 + quad * 8;
            #pragma unroll
            for (int ks = 0; ks < 8; ++ks) {
                bf16x8 A = *(const bf16x8*)&hbuf[hsw_chunk(ln, ks, quad)];
                #pragma unroll
                for (int ct = 0; ct < 2; ++ct) {
                    bf16x8 Bv = *(const bf16x8*)(wb + (size_t)ct * 16 * 256 + ks * 32);
                    acc[ct] = __builtin_amdgcn_mfma_f32_16x16x32_bf16(A, Bv, acc[ct], 0, 0, 0);
                }
            }
            float vv[2][4];
            #pragma unroll
            for (int ct = 0; ct < 2; ++ct) {
                const int col = cb + ct * 16 + ln;
                const float bb = ff_b2[l * 256 + col];
                #pragma unroll
                for (int r = 0; r < 4; ++r) {
                    const int row = quad * 4 + r;
                    vv[ct][r] = (row < 8) ? (acc[ct][r] + bb + avF[row][col]) : 0.f;
                }
            }
            #pragma unroll
            for (int r = 0; r < 4; ++r) {
                const int row = quad * 4 + r;
                float sl = vv[0][r] + vv[1][r];
                float ql = vv[0][r] * vv[0][r] + vv[1][r] * vv[1][r];
                #pragma unroll
                for (int off = 8; off >= 1; off >>= 1) {
                    sl += __shfl_xor(sl, off);
                    ql += __shfl_xor(ql, off);
                }
                if (ln == 0 && row < 8) {
                    psum[row][w] = sl; psq[row][w] = ql;
                }
            }
            __syncthreads();
            #pragma unroll
            for (int r = 0; r < 4; ++r) {
                const int row = quad * 4 + r;
                if (row < 8) {
                    float sl = 0.f, ql = 0.f;
                    #pragma unroll
                    for (int j = 0; j < 8; ++j) { sl += psum[row][j]; ql += psq[row][j]; }
                    const float mu = sl * (1.0f / 256.0f);
                    const float var = ql * (1.0f / 256.0f) - mu * mu;
                    const float rstd = 1.0f / sqrtf(fmaxf(var, 0.f) + 1e-5f);
                    #pragma unroll
                    for (int ct = 0; ct < 2; ++ct) {
                        const int col = cb + ct * 16 + ln;
                        float o = (vv[ct][r] - mu) * rstd * ln2_g[l * 256 + col] + ln2_b[l * 256 + col];
                        avF[row][col] = o;
                        abuf[hsw_elem(row, col)] = f2bf(o);
                    }
                }
            }
        }
        __syncthreads();
    }

    // ==================== decoder + loss ====================
    // stage 1: h1 = relu(abuf @ deW1 + b1) -> hbuf
    {
        const unsigned short* W1 = Wm + (size_t)5 * 65536;
        f32x4 acc[2]; acc[0] = zero; acc[1] = zero;
        const unsigned short* wb = W1 + (size_t)(cb + ln) * 256 + quad * 8;
        #pragma unroll
        for (int ks = 0; ks < 8; ++ks) {
            bf16x8 A = *(const bf16x8*)&abuf[hsw_chunk(ln, ks, quad)];
            #pragma unroll
            for (int ct = 0; ct < 2; ++ct) {
                bf16x8 Bv = *(const bf16x8*)(wb + (size_t)ct * 16 * 256 + ks * 32);
                acc[ct] = __builtin_amdgcn_mfma_f32_16x16x32_bf16(A, Bv, acc[ct], 0, 0, 0);
            }
        }
        #pragma unroll
        for (int ct = 0; ct < 2; ++ct) {
            const int col = cb + ct * 16 + ln;
            const float bb = de_b1[col];
            #pragma unroll
            for (int r = 0; r < 4; ++r) {
                const int row = quad * 4 + r;
                if (row < 8)
                    hbuf[hsw_elem(row, col)] = f2bf(fmaxf(acc[ct][r] + bb, 0.f));
            }
        }
    }
    __syncthreads();

    // stage 2: h2 = relu(hbuf @ deW2 + b2) -> hbuf (barrier-separated)
    {
        const unsigned short* W2 = Wm + (size_t)6 * 65536;
        f32x4 acc[2]; acc[0] = zero; acc[1] = zero;
        const unsigned short* wb = W2 + (size_t)(cb + ln) * 256 + quad * 8;
        #pragma unroll
        for (int ks = 0; ks < 8; ++ks) {
            bf16x8 A = *(const bf16x8*)&hbuf[hsw_chunk(ln, ks, quad)];
            #pragma unroll
            for (int ct = 0; ct < 2; ++ct) {
                bf16x8 Bv = *(const bf16x8*)(wb + (size_t)ct * 16 * 256 + ks * 32);
                acc[ct] = __builtin_amdgcn_mfma_f32_16x16x32_bf16(A, Bv, acc[ct], 0, 0, 0);
            }
        }
        __syncthreads();
        #pragma unroll
        for (int ct = 0; ct < 2; ++ct) {
            const int col = cb + ct * 16 + ln;
            const float bb = de_b2[col];
            #pragma unroll
            for (int r = 0; r < 4; ++r) {
                const int row = quad * 4 + r;
                if (row < 8)
                    hbuf[hsw_elem(row, col)] = f2bf(fmaxf(acc[ct][r] + bb, 0.f));
            }
        }
    }
    __syncthreads();

    // stage 3: logits (128 cols; wave w -> cols w*16..+15) + loss
    {
        const unsigned short* W3 = Wm + (size_t)7 * 65536;
        const int cb3 = w * 16;
        f32x4 a3 = zero;
        const unsigned short* wb = W3 + (size_t)(cb3 + ln) * 256 + quad * 8;
        #pragma unroll
        for (int ks = 0; ks < 8; ++ks) {
            bf16x8 A = *(const bf16x8*)&hbuf[hsw_chunk(ln, ks, quad)];
            bf16x8 Bv = *(const bf16x8*)(wb + ks * 32);
            a3 = __builtin_amdgcn_mfma_f32_16x16x32_bf16(A, Bv, a3, 0, 0, 0);
        }
        float lg[4];
        const float bb = de_b3[cb3 + ln];
        #pragma unroll
        for (int r = 0; r < 4; ++r) lg[r] = a3[r] + bb;

        // row-max partials (psum/psq reused as pmax/pxt scratch)
        #pragma unroll
        for (int r = 0; r < 4; ++r) {
            const int row = quad * 4 + r;
            float m = lg[r];
            #pragma unroll
            for (int off = 8; off >= 1; off >>= 1) m = fmaxf(m, __shfl_xor(m, off));
            if (ln == 0 && row < 8) psum[row][w] = m;
        }
        __syncthreads();
        if (tid < 8) {
            float m = psum[tid][0];
            #pragma unroll
            for (int j = 1; j < 8; ++j) m = fmaxf(m, psum[tid][j]);
            rowmax[tid] = m;
            float tu = true_u[(size_t)b * Vc + pps[tid]];
            int t = (int)floorf(tu * 128.0f);
            tcol[tid] = t < 0 ? 0 : (t > 127 ? 127 : t);
        }
        __syncthreads();
        #pragma unroll
        for (int r = 0; r < 4; ++r) {
            const int row = quad * 4 + r;
            float e = 0.f, xt = 0.f;
            if (row < 8) {
                const float mx = rowmax[row];
                const int t = tcol[row];
                e = expf(lg[r] - mx);
                xt = ((cb3 + ln) == t) ? lg[r] : 0.f;
            }
            #pragma unroll
            for (int off = 8; off >= 1; off >>= 1) {
                e += __shfl_xor(e, off);
                xt += __shfl_xor(xt, off);
            }
            if (ln == 0 && row < 8) { psum[row][w] = e; psq[row][w] = xt; }
        }
        __syncthreads();
        float contrib = 0.f;
        if (tid < 8) {
            float sum = 0.f, xt = 0.f;
            #pragma unroll
            for (int j = 0; j < 8; ++j) { sum += psum[tid][j]; xt += psq[tid][j]; }
            const float lp = logf(128.0f) + (xt - rowmax[tid]) - logf(sum);
            contrib = -lp;
        }
        if (w == 0) {
            #pragma unroll
            for (int off = 32; off >= 1; off >>= 1) contrib += __shfl_xor(contrib, off);
            if (lane == 0) atomicAdd(&outp[b], contrib);
        }
    }
}

// ---------------------------------------------------------------------------
extern "C" void kernel_launch(void* const* d_in, const int* in_sizes, int n_in,
                              void* d_out, int out_size, void* d_ws, size_t ws_size,
                              hipStream_t stream)
{
    (void)in_sizes; (void)n_in; (void)out_size; (void)ws_size;

    const float* encoded        = (const float*)d_in[0];
    const float* true_u         = (const float*)d_in[1];
    const float* attn_mask      = (const float*)d_in[2];
    const int*   pred_points    = (const int*)d_in[3];
    const int*   neighbor_index = (const int*)d_in[4];
    const float* kW1 = (const float*)d_in[5];
    const float* kb1 = (const float*)d_in[6];
    const float* kW2 = (const float*)d_in[7];
    const float* kb2 = (const float*)d_in[8];
    const float* kW3 = (const float*)d_in[9];
    const float* kb3 = (const float*)d_in[10];
    const float* vW1 = (const float*)d_in[11];
    const float* vb1 = (const float*)d_in[12];
    const float* vW2 = (const float*)d_in[13];
    const float* vb2 = (const float*)d_in[14];
    const float* vW3 = (const float*)d_in[15];
    const float* vb3 = (const float*)d_in[16];
    const float* ds_W  = (const float*)d_in[17];
    const float* ds_b  = (const float*)d_in[18];
    const float* ln1_g = (const float*)d_in[19];
    const float* ln1_b = (const float*)d_in[20];
    const float* ff_W1 = (const float*)d_in[21];
    const float* ff_b1 = (const float*)d_in[22];
    const float* ff_W2 = (const float*)d_in[23];
    const float* ff_b2 = (const float*)d_in[24];
    const float* ln2_g = (const float*)d_in[25];
    const float* ln2_b = (const float*)d_in[26];
    const float* de_W1 = (const float*)d_in[27];
    const float* de_b1 = (const float*)d_in[28];
    const float* de_W2 = (const float*)d_in[29];
    const float* de_b2 = (const float*)d_in[30];
    const float* de_W3 = (const float*)d_in[31];
    const float* de_b3 = (const float*)d_in[32];

    float* out = (float*)d_out;

    // workspace layout
    constexpr size_t KV_ELEMS = (size_t)Lc * Bc * Hc * Vc * 32;  // 8,388,608
    unsigned short* keys = (unsigned short*)d_ws;            // bf16 [l][b][v][256]
    unsigned short* vals = keys + KV_ELEMS;
    unsigned short* Xbf  = vals + KV_ELEMS;                  // 16384 x 256 bf16
    unsigned short* W1t  = Xbf + (size_t)ROWS_KV * 256;      // 32 nets x [256][256]
    unsigned short* W2t  = W1t + (size_t)32 * 65536;
    unsigned short* W3t  = W2t + (size_t)32 * 65536;         // 32 nets x [32][256]
    unsigned short* Wm   = W3t + (size_t)32 * 8192;          // 8 slots x 65536

    (void)hipMemsetAsync(out, 0, Bc * sizeof(float), stream);

    // prep
    conv_x_kernel<<<dim3(ROWS_KV * 256 / 4 / 256), 256, 0, stream>>>(encoded, Xbf);
    transpose_all_kernel<<<dim3(8, 8, 104), 256, 0, stream>>>(
        kW1, vW1, kW2, vW2, kW3, vW3,
        ds_W, ff_W1, ff_W2, de_W1, de_W2, de_W3,
        W1t, W2t, W3t, Wm);

    // KV MLPs v7b: 16 rg x 16 (l,h) x {k,v}
    kv_mfma_kernel<<<dim3(16, 16, 2), 512, 0, stream>>>(
        Xbf, true_u, W1t, W2t, W3t, kW1, vW1,
        kb1, kb2, kb3, vb1, vb2, vb3, keys, vals);

    // fused tail: 512 blocks x 8 rows (2 blocks/CU)
    decoder_kernel<<<dim3(ROWS_AT / 8), 512, 0, stream>>>(
        Xbf, true_u, keys, vals, neighbor_index, attn_mask, pred_points, Wm,
        ds_b, ln1_g, ln1_b, ff_b1, ff_b2, ln2_g, ln2_b,
        de_b1, de_b2, de_b3, out);
}

// Round 18
// 451.889 us; speedup vs baseline: 1.0703x; 1.0703x over previous
//
#include <hip/hip_runtime.h>
#include <hip/hip_bf16.h>
#include <cstdint>
#include <cstddef>

// Problem dims (compile-time)
constexpr int Bc = 8;
constexpr int Vc = 2048;   // S*T
constexpr int Pc = 512;
constexpr int Hc = 8;
constexpr int Lc = 2;
constexpr int ROWS_KV = Bc * Vc;   // 16384
constexpr int ROWS_AT = Bc * Pc;   // 4096

typedef __attribute__((ext_vector_type(8))) short bf16x8;   // 8 bf16 (4 VGPRs)
typedef __attribute__((ext_vector_type(4))) float f32x4;

static __device__ __forceinline__ unsigned short f2bf(float v) {
    __hip_bfloat16 h = __float2bfloat16(v);
    return *(unsigned short*)&h;
}
static __device__ __forceinline__ float bflo(unsigned int u) {
    return __uint_as_float(u << 16);
}
static __device__ __forceinline__ float bfhi(unsigned int u) {
    return __uint_as_float(u & 0xffff0000u);
}

// ---------------------------------------------------------------------------
// Prep: encoded fp32 -> bf16 (row-major [16384][256])
// ---------------------------------------------------------------------------
__global__ __launch_bounds__(256) void conv_x_kernel(
    const float* __restrict__ x, unsigned short* __restrict__ xb)
{
    const int i = blockIdx.x * 256 + threadIdx.x;   // 1 float4 per thread
    float4 v = ((const float4*)x)[i];
    ushort4 o;
    o.x = f2bf(v.x); o.y = f2bf(v.y); o.z = f2bf(v.z); o.w = f2bf(v.w);
    ((ushort4*)xb)[i] = o;
}

// ---------------------------------------------------------------------------
// Merged prep: all weight transposes [K x C] fp32 -> [C x 256] bf16.
// ---------------------------------------------------------------------------
__global__ __launch_bounds__(256) void transpose_all_kernel(
    const float* kW1, const float* vW1, const float* kW2, const float* vW2,
    const float* kW3, const float* vW3,
    const float* ds_W, const float* ff_W1, const float* ff_W2,
    const float* de_W1, const float* de_W2, const float* de_W3,
    unsigned short* __restrict__ W1t, unsigned short* __restrict__ W2t,
    unsigned short* __restrict__ W3t, unsigned short* __restrict__ Wm)
{
    const int z = blockIdx.z;
    const float* src;
    unsigned short* dst;
    int C;
    if (z < 32) {
        const int net = z;
        src = ((net >> 4) ? vW1 : kW1) + (size_t)(net & 15) * 257 * 256;
        dst = W1t + (size_t)net * 65536;
        C = 256;
    } else if (z < 64) {
        const int net = z - 32;
        src = ((net >> 4) ? vW2 : kW2) + (size_t)(net & 15) * 256 * 256;
        dst = W2t + (size_t)net * 65536;
        C = 256;
    } else if (z < 96) {
        const int net = z - 64;
        src = ((net >> 4) ? vW3 : kW3) + (size_t)(net & 15) * 256 * 32;
        dst = W3t + (size_t)net * 8192;
        C = 32;
    } else {
        const int id = z - 96;
        const float* srcs[8] = {ds_W, ff_W1, ff_W1 + (size_t)65536,
                                ff_W2, ff_W2 + (size_t)65536, de_W1, de_W2, de_W3};
        src = srcs[id];
        dst = Wm + (size_t)id * 65536;
        C = (id == 7) ? 128 : 256;
    }
    if (blockIdx.x * 32 >= C) return;
    __shared__ float t[32][33];
    const int c0 = blockIdx.x * 32, k0 = blockIdx.y * 32;
    const int tx = threadIdx.x & 31, ty = threadIdx.x >> 5;
    #pragma unroll
    for (int i = 0; i < 32; i += 8)
        t[ty + i][tx] = src[(size_t)(k0 + ty + i) * C + (c0 + tx)];
    __syncthreads();
    #pragma unroll
    for (int i = 0; i < 32; i += 8)
        dst[(size_t)(c0 + ty + i) * 256 + (k0 + tx)] = f2bf(t[tx][ty + i]);
}

// h-buf XOR swizzle: rows x 256 shorts (32 chunks of 8 shorts).
static __device__ __forceinline__ int hsw_chunk(int row, int ks, int quad) {
    int c = ks * 4 + quad;
    int p = c ^ (row & 31);
    return row * 256 + p * 8;
}
static __device__ __forceinline__ int hsw_elem(int row, int col) {
    int p = (col >> 3) ^ (row & 31);
    return row * 256 + p * 8 + (col & 7);
}

// ---------------------------------------------------------------------------
// Fused 3-layer KV MLP — v7b (best measured): weight-resident W1/W2 in
// registers, W3 in 16KB swizzled LDS, 8 waves, 512 blocks.
// Output bf16 [l][b][v][h*32].
// ---------------------------------------------------------------------------
__global__ __launch_bounds__(512, 2) void kv_mfma_kernel(
    const unsigned short* __restrict__ Xbf, const float* __restrict__ true_u,
    const unsigned short* __restrict__ W1t, const unsigned short* __restrict__ W2t,
    const unsigned short* __restrict__ W3t,
    const float* __restrict__ kW1, const float* __restrict__ vW1,
    const float* __restrict__ kb1, const float* __restrict__ kb2, const float* __restrict__ kb3,
    const float* __restrict__ vb1, const float* __restrict__ vb2, const float* __restrict__ vb3,
    unsigned short* __restrict__ keys, unsigned short* __restrict__ vals)
{
    __shared__ unsigned short hbuf[64 * 256];    // 32 KB: X -> h1 -> h2 (swizzled)
    __shared__ unsigned short w3buf[32 * 256];   // 16 KB: W3 slice (swizzled)
    __shared__ float tub[64];                    // true_u tile

    const int tid = threadIdx.x;
    const int w = tid >> 6, lane = tid & 63;
    const int ln = lane & 15, quad = lane >> 4;
    const int lh = blockIdx.y, isv = blockIdx.z;
    const int net = isv * 16 + lh;
    const float* W1f = (isv ? vW1 : kW1) + (size_t)lh * 257 * 256;
    const float* b1  = (isv ? vb1 : kb1) + lh * 256;
    const float* b2  = (isv ? vb2 : kb2) + lh * 256;
    const float* b3  = (isv ? vb3 : kb3) + lh * 32;
    const unsigned short* w1 = W1t + (size_t)net * 65536;
    const unsigned short* w2 = W2t + (size_t)net * 65536;
    const unsigned short* w3 = W3t + (size_t)net * 8192;
    unsigned short* outp = isv ? vals : keys;
    const int base = blockIdx.x * 1024;          // row-group (16 tiles)
    const int cb = w * 32;                       // wave's column base (stages 1-2)

    // ---- one-time: W1/W2 column slices -> registers ----
    bf16x8 B1[16], B2[16];
    {
        const unsigned short* p1 = w1 + (size_t)(cb + ln) * 256 + quad * 8;
        const unsigned short* p2 = w2 + (size_t)(cb + ln) * 256 + quad * 8;
        #pragma unroll
        for (int ks = 0; ks < 8; ++ks)
            #pragma unroll
            for (int ct = 0; ct < 2; ++ct) {
                B1[ks * 2 + ct] = *(const bf16x8*)(p1 + (size_t)ct * 16 * 256 + ks * 32);
                B2[ks * 2 + ct] = *(const bf16x8*)(p2 + (size_t)ct * 16 * 256 + ks * 32);
            }
    }
    // ---- one-time: W3 -> swizzled LDS ----
    {
        #pragma unroll
        for (int j = 0; j < 2; ++j) {
            const int cidx = tid * 2 + j;
            const int col = cidx >> 5, c = cidx & 31;
            uint4 d = *(const uint4*)(w3 + cidx * 8);
            *(uint4*)&w3buf[col * 256 + (c ^ (col & 31)) * 8] = d;
        }
    }
    float w1f[2], b1v[2], b2v[2];
    #pragma unroll
    for (int ct = 0; ct < 2; ++ct) {
        const int col = cb + ct * 16 + ln;
        w1f[ct] = W1f[256 * 256 + col];
        b1v[ct] = b1[col];
        b2v[ct] = b2[col];
    }
    const int rt3 = w & 3, ct3 = w >> 2;
    const float b3v = b3[ct3 * 16 + ln];

    const int b_ = base >> 11;
    const int l_ = lh >> 3, h_ = lh & 7;
    unsigned short* ob = outp + (((size_t)l_ * Bc + b_) * Vc) * 256 + h_ * 32;

    const f32x4 zero = {0.f, 0.f, 0.f, 0.f};
    const int xr = tid >> 3, cg = tid & 7;

    for (int t = 0; t < 16; ++t) {
        const int row0 = base + t * 64;
        __syncthreads();

        {
            const unsigned short* gx = Xbf + (size_t)(row0 + xr) * 256;
            #pragma unroll
            for (int j = 0; j < 4; ++j) {
                const int c = j * 8 + cg;
                uint4 d = *(const uint4*)(gx + c * 8);
                *(uint4*)&hbuf[xr * 256 + (c ^ (xr & 31)) * 8] = d;
            }
            if (tid < 64) tub[tid] = true_u[row0 + tid];
        }
        __syncthreads();

        // ---- stage 1 ----
        f32x4 acc[4][2];
        #pragma unroll
        for (int rt = 0; rt < 4; ++rt)
            #pragma unroll
            for (int ct = 0; ct < 2; ++ct) acc[rt][ct] = zero;
        #pragma unroll
        for (int ks = 0; ks < 8; ++ks) {
            bf16x8 A[4];
            #pragma unroll
            for (int rt = 0; rt < 4; ++rt)
                A[rt] = *(const bf16x8*)&hbuf[hsw_chunk(rt * 16 + ln, ks, quad)];
            #pragma unroll
            for (int rt = 0; rt < 4; ++rt)
                #pragma unroll
                for (int ct = 0; ct < 2; ++ct)
                    acc[rt][ct] = __builtin_amdgcn_mfma_f32_16x16x32_bf16(A[rt], B1[ks * 2 + ct], acc[rt][ct], 0, 0, 0);
        }
        __syncthreads();
        #pragma unroll
        for (int ct = 0; ct < 2; ++ct) {
            const int col = cb + ct * 16 + ln;
            #pragma unroll
            for (int rt = 0; rt < 4; ++rt)
                #pragma unroll
                for (int r = 0; r < 4; ++r) {
                    const int row = rt * 16 + quad * 4 + r;
                    float v = fmaxf(acc[rt][ct][r] + b1v[ct] + tub[row] * w1f[ct], 0.f);
                    hbuf[hsw_elem(row, col)] = f2bf(v);
                }
        }
        __syncthreads();

        // ---- stage 2 ----
        #pragma unroll
        for (int rt = 0; rt < 4; ++rt)
            #pragma unroll
            for (int ct = 0; ct < 2; ++ct) acc[rt][ct] = zero;
        #pragma unroll
        for (int ks = 0; ks < 8; ++ks) {
            bf16x8 A[4];
            #pragma unroll
            for (int rt = 0; rt < 4; ++rt)
                A[rt] = *(const bf16x8*)&hbuf[hsw_chunk(rt * 16 + ln, ks, quad)];
            #pragma unroll
            for (int rt = 0; rt < 4; ++rt)
                #pragma unroll
                for (int ct = 0; ct < 2; ++ct)
                    acc[rt][ct] = __builtin_amdgcn_mfma_f32_16x16x32_bf16(A[rt], B2[ks * 2 + ct], acc[rt][ct], 0, 0, 0);
        }
        __syncthreads();
        #pragma unroll
        for (int ct = 0; ct < 2; ++ct) {
            const int col = cb + ct * 16 + ln;
            #pragma unroll
            for (int rt = 0; rt < 4; ++rt)
                #pragma unroll
                for (int r = 0; r < 4; ++r) {
                    const int row = rt * 16 + quad * 4 + r;
                    hbuf[hsw_elem(row, col)] = f2bf(fmaxf(acc[rt][ct][r] + b2v[ct], 0.f));
                }
        }
        __syncthreads();

        // ---- stage 3 ----
        f32x4 acc3 = zero;
        #pragma unroll
        for (int ks = 0; ks < 8; ++ks) {
            bf16x8 A  = *(const bf16x8*)&hbuf[hsw_chunk(rt3 * 16 + ln, ks, quad)];
            bf16x8 Bv = *(const bf16x8*)&w3buf[hsw_chunk(ct3 * 16 + ln, ks, quad)];
            acc3 = __builtin_amdgcn_mfma_f32_16x16x32_bf16(A, Bv, acc3, 0, 0, 0);
        }
        #pragma unroll
        for (int r = 0; r < 4; ++r) {
            const int grow = row0 + rt3 * 16 + quad * 4 + r;
            ob[(size_t)(grow & 2047) * 256 + ct3 * 16 + ln] = f2bf(acc3[r] + b3v);
        }
    }
}

// ---------------------------------------------------------------------------
// FUSED TAIL (R16 shape + row-interleaved attention): per block = 16 rows,
// 256 blocks, 512 threads.  Attention: wave w owns rows w*2 and w*2+1,
// INTERLEAVED inside the head loop (2 independent chains for ILP).
// ---------------------------------------------------------------------------
__global__ __launch_bounds__(512) void decoder_kernel(
    const unsigned short* __restrict__ Xbf, const float* __restrict__ true_u,
    const unsigned short* __restrict__ keys, const unsigned short* __restrict__ vals,
    const int* __restrict__ nbr, const float* __restrict__ mask,
    const int* __restrict__ pp, const unsigned short* __restrict__ Wm,
    const float* __restrict__ ds_b,
    const float* __restrict__ ln1_g, const float* __restrict__ ln1_b,
    const float* __restrict__ ff_b1, const float* __restrict__ ff_b2,
    const float* __restrict__ ln2_g, const float* __restrict__ ln2_b,
    const float* __restrict__ de_b1, const float* __restrict__ de_b2,
    const float* __restrict__ de_b3, float* __restrict__ outp)
{
    __shared__ float avF[16][264];
    __shared__ float attF[16][264];
    __shared__ unsigned short abuf[16 * 256];
    __shared__ unsigned short hbuf[16 * 256];
    __shared__ int   ni_s[16][64];
    __shared__ float wtsb[16][64];
    __shared__ float psum[16][8], psq[16][8];
    __shared__ float rowmax[16];
    __shared__ int   tcol[16];
    __shared__ int   pps[16];

    const int tid = threadIdx.x;
    const int w = tid >> 6, lane = tid & 63;
    const int ln = lane & 15, quad = lane >> 4;
    const int bid = blockIdx.x;
    const int b = bid & 7;                       // XCD-affine batch
    const int r0 = b * 512 + (bid >> 3) * 16;    // global row base
    const int cb = w * 32;                       // GEMM column base

    const f32x4 zero = {0.f, 0.f, 0.f, 0.f};

    // ---- init: pp values + neighbor indices ----
    if (tid < 16) pps[tid] = pp[(r0 + tid) & 511];
    #pragma unroll
    for (int j = 0; j < 2; ++j) {
        const int idx = tid * 2 + j;             // 1024 = 16*64
        const int row = idx >> 6, n = idx & 63;
        ni_s[row][n] = nbr[((r0 + row) & 511) * 64 + n];
    }
    __syncthreads();

    // ---- gather X rows into abuf ----
    {
        const int row = tid >> 5, c = tid & 31;
        const size_t arow = (size_t)b * Vc + pps[row];
        uint4 d = *(const uint4*)(Xbf + arow * 256 + c * 8);
        *(uint4*)&abuf[row * 256 + ((c ^ row) * 8)] = d;
    }
    __syncthreads();

    // ---- ds GEMM ----
    {
        const unsigned short* Wt = Wm;
        f32x4 acc[2]; acc[0] = zero; acc[1] = zero;
        const unsigned short* wb = Wt + (size_t)(cb + ln) * 256 + quad * 8;
        #pragma unroll
        for (int ks = 0; ks < 8; ++ks) {
            bf16x8 A = *(const bf16x8*)&abuf[hsw_chunk(ln, ks, quad)];
            #pragma unroll
            for (int ct = 0; ct < 2; ++ct) {
                bf16x8 Bv = *(const bf16x8*)(wb + (size_t)ct * 16 * 256 + ks * 32);
                acc[ct] = __builtin_amdgcn_mfma_f32_16x16x32_bf16(A, Bv, acc[ct], 0, 0, 0);
            }
        }
        __syncthreads();
        #pragma unroll
        for (int ct = 0; ct < 2; ++ct) {
            const int col = cb + ct * 16 + ln;
            const float bb = ds_b[col];
            #pragma unroll
            for (int r = 0; r < 4; ++r) {
                const int row = quad * 4 + r;
                float v = acc[ct][r] + bb;
                avF[row][col] = v;
                abuf[hsw_elem(row, col)] = f2bf(v);
            }
        }
    }
    __syncthreads();

    // ==================== transformer layers ====================
    for (int l = 0; l < Lc; ++l) {
        const unsigned short* kvb = keys + (((size_t)l * Bc + b) * Vc) * 256;
        const unsigned short* vvb = vals + (((size_t)l * Bc + b) * Vc) * 256;

        // ---- attention: rows w*2 and w*2+1 interleaved in the head loop ----
        {
            const int row0a = w * 2, row1a = w * 2 + 1;
            const int p0 = (r0 + row0a) & 511, p1 = (r0 + row1a) & 511;
            const int n = lane;
            const int vi0 = ni_s[row0a][n], vi1 = ni_s[row1a][n];
            const float m0 = mask[p0 * 64 + n], m1 = mask[p1 * 64 + n];
            for (int h = 0; h < 8; ++h) {
                // q for both rows (broadcast LDS reads)
                float q0[32], q1[32];
                #pragma unroll
                for (int j = 0; j < 8; ++j) {
                    float4 t0 = *(const float4*)&avF[row0a][h * 32 + j * 4];
                    float4 t1 = *(const float4*)&avF[row1a][h * 32 + j * 4];
                    q0[j * 4 + 0] = t0.x; q0[j * 4 + 1] = t0.y;
                    q0[j * 4 + 2] = t0.z; q0[j * 4 + 3] = t0.w;
                    q1[j * 4 + 0] = t1.x; q1[j * 4 + 1] = t1.y;
                    q1[j * 4 + 2] = t1.z; q1[j * 4 + 3] = t1.w;
                }
                // two independent score chains
                const unsigned short* kp0 = kvb + (size_t)vi0 * 256 + h * 32;
                const unsigned short* kp1 = kvb + (size_t)vi1 * 256 + h * 32;
                float s0 = 0.f, s1 = 0.f;
                #pragma unroll
                for (int j = 0; j < 4; ++j) {
                    uint4 u0 = *(const uint4*)(kp0 + j * 8);
                    uint4 u1 = *(const uint4*)(kp1 + j * 8);
                    s0 += q0[j * 8 + 0] * bflo(u0.x) + q0[j * 8 + 1] * bfhi(u0.x);
                    s1 += q1[j * 8 + 0] * bflo(u1.x) + q1[j * 8 + 1] * bfhi(u1.x);
                    s0 += q0[j * 8 + 2] * bflo(u0.y) + q0[j * 8 + 3] * bfhi(u0.y);
                    s1 += q1[j * 8 + 2] * bflo(u1.y) + q1[j * 8 + 3] * bfhi(u1.y);
                    s0 += q0[j * 8 + 4] * bflo(u0.z) + q0[j * 8 + 5] * bfhi(u0.z);
                    s1 += q1[j * 8 + 4] * bflo(u1.z) + q1[j * 8 + 5] * bfhi(u1.z);
                    s0 += q0[j * 8 + 6] * bflo(u0.w) + q0[j * 8 + 7] * bfhi(u0.w);
                    s1 += q1[j * 8 + 6] * bflo(u1.w) + q1[j * 8 + 7] * bfhi(u1.w);
                }
                s0 = (s0 - m0) * 0.17677669529663689f;
                s1 = (s1 - m1) * 0.17677669529663689f;
                // interleaved softmax butterflies
                float mx0 = s0, mx1 = s1;
                #pragma unroll
                for (int off = 32; off >= 1; off >>= 1) {
                    mx0 = fmaxf(mx0, __shfl_xor(mx0, off));
                    mx1 = fmaxf(mx1, __shfl_xor(mx1, off));
                }
                float e0 = expf(s0 - mx0), e1 = expf(s1 - mx1);
                float sum0 = e0, sum1 = e1;
                #pragma unroll
                for (int off = 32; off >= 1; off >>= 1) {
                    sum0 += __shfl_xor(sum0, off);
                    sum1 += __shfl_xor(sum1, off);
                }
                wtsb[row0a][n] = e0 / sum0;
                wtsb[row1a][n] = e1 / sum1;
                // PV both rows, vectorized + interleaved
                const int nb4 = n >> 2, cg8 = (n & 3) * 8;
                float a0[8], a1[8];
                #pragma unroll
                for (int j = 0; j < 8; ++j) { a0[j] = 0.f; a1[j] = 0.f; }
                #pragma unroll
                for (int pass = 0; pass < 4; ++pass) {
                    const int nn = pass * 16 + nb4;
                    const float w0 = wtsb[row0a][nn], w1 = wtsb[row1a][nn];
                    const unsigned short* vp0 = vvb + (size_t)ni_s[row0a][nn] * 256 + h * 32 + cg8;
                    const unsigned short* vp1 = vvb + (size_t)ni_s[row1a][nn] * 256 + h * 32 + cg8;
                    uint4 u0 = *(const uint4*)vp0;
                    uint4 u1 = *(const uint4*)vp1;
                    a0[0] += w0 * bflo(u0.x); a0[1] += w0 * bfhi(u0.x);
                    a1[0] += w1 * bflo(u1.x); a1[1] += w1 * bfhi(u1.x);
                    a0[2] += w0 * bflo(u0.y); a0[3] += w0 * bfhi(u0.y);
                    a1[2] += w1 * bflo(u1.y); a1[3] += w1 * bfhi(u1.y);
                    a0[4] += w0 * bflo(u0.z); a0[5] += w0 * bfhi(u0.z);
                    a1[4] += w1 * bflo(u1.z); a1[5] += w1 * bfhi(u1.z);
                    a0[6] += w0 * bflo(u0.w); a0[7] += w0 * bfhi(u0.w);
                    a1[6] += w1 * bflo(u1.w); a1[7] += w1 * bfhi(u1.w);
                }
                #pragma unroll
                for (int off = 4; off <= 32; off <<= 1)
                    #pragma unroll
                    for (int j = 0; j < 8; ++j) {
                        a0[j] += __shfl_xor(a0[j], off);
                        a1[j] += __shfl_xor(a1[j], off);
                    }
                if (nb4 == 0)
                    #pragma unroll
                    for (int j = 0; j < 8; ++j) {
                        attF[row0a][h * 32 + cg8 + j] = a0[j];
                        attF[row1a][h * 32 + cg8 + j] = a1[j];
                    }
            }
            // LN1 for both rows (in-wave)
            #pragma unroll
            for (int rr = 0; rr < 2; ++rr) {
                const int row = w * 2 + rr;
                const int c0 = lane * 4;
                float x[4];
                float sl = 0.f, ql = 0.f;
                #pragma unroll
                for (int j = 0; j < 4; ++j) {
                    x[j] = avF[row][c0 + j] + attF[row][c0 + j];
                    sl += x[j]; ql += x[j] * x[j];
                }
                #pragma unroll
                for (int off = 32; off >= 1; off >>= 1) {
                    sl += __shfl_xor(sl, off);
                    ql += __shfl_xor(ql, off);
                }
                const float mu = sl * (1.0f / 256.0f);
                const float var = ql * (1.0f / 256.0f) - mu * mu;
                const float rstd = 1.0f / sqrtf(fmaxf(var, 0.f) + 1e-5f);
                #pragma unroll
                for (int j = 0; j < 4; ++j) {
                    const int col = c0 + j;
                    float o = (x[j] - mu) * rstd * ln1_g[l * 256 + col] + ln1_b[l * 256 + col];
                    avF[row][col] = o;
                    abuf[hsw_elem(row, col)] = f2bf(o);
                }
            }
        }
        __syncthreads();

        // ---- ff stage A: T1 = relu(abuf @ W1 + b1) -> hbuf ----
        {
            const unsigned short* W1 = Wm + (size_t)(1 + l) * 65536;
            f32x4 acc[2]; acc[0] = zero; acc[1] = zero;
            const unsigned short* wb = W1 + (size_t)(cb + ln) * 256 + quad * 8;
            #pragma unroll
            for (int ks = 0; ks < 8; ++ks) {
                bf16x8 A = *(const bf16x8*)&abuf[hsw_chunk(ln, ks, quad)];
                #pragma unroll
                for (int ct = 0; ct < 2; ++ct) {
                    bf16x8 Bv = *(const bf16x8*)(wb + (size_t)ct * 16 * 256 + ks * 32);
                    acc[ct] = __builtin_amdgcn_mfma_f32_16x16x32_bf16(A, Bv, acc[ct], 0, 0, 0);
                }
            }
            #pragma unroll
            for (int ct = 0; ct < 2; ++ct) {
                const int col = cb + ct * 16 + ln;
                const float bb = ff_b1[l * 256 + col];
                #pragma unroll
                for (int r = 0; r < 4; ++r) {
                    const int row = quad * 4 + r;
                    hbuf[hsw_elem(row, col)] = f2bf(fmaxf(acc[ct][r] + bb, 0.f));
                }
            }
        }
        __syncthreads();

        // ---- ff stage B + residual + LN2 ----
        {
            const unsigned short* W2 = Wm + (size_t)(3 + l) * 65536;
            f32x4 acc[2]; acc[0] = zero; acc[1] = zero;
            const unsigned short* wb = W2 + (size_t)(cb + ln) * 256 + quad * 8;
            #pragma unroll
            for (int ks = 0; ks < 8; ++ks) {
                bf16x8 A = *(const bf16x8*)&hbuf[hsw_chunk(ln, ks, quad)];
                #pragma unroll
                for (int ct = 0; ct < 2; ++ct) {
                    bf16x8 Bv = *(const bf16x8*)(wb + (size_t)ct * 16 * 256 + ks * 32);
                    acc[ct] = __builtin_amdgcn_mfma_f32_16x16x32_bf16(A, Bv, acc[ct], 0, 0, 0);
                }
            }
            float vv[2][4];
            #pragma unroll
            for (int ct = 0; ct < 2; ++ct) {
                const int col = cb + ct * 16 + ln;
                const float bb = ff_b2[l * 256 + col];
                #pragma unroll
                for (int r = 0; r < 4; ++r) {
                    const int row = quad * 4 + r;
                    vv[ct][r] = acc[ct][r] + bb + avF[row][col];
                }
            }
            #pragma unroll
            for (int r = 0; r < 4; ++r) {
                float sl = vv[0][r] + vv[1][r];
                float ql = vv[0][r] * vv[0][r] + vv[1][r] * vv[1][r];
                #pragma unroll
                for (int off = 8; off >= 1; off >>= 1) {
                    sl += __shfl_xor(sl, off);
                    ql += __shfl_xor(ql, off);
                }
                if (ln == 0) {
                    const int row = quad * 4 + r;
                    psum[row][w] = sl; psq[row][w] = ql;
                }
            }
            __syncthreads();
            #pragma unroll
            for (int r = 0; r < 4; ++r) {
                const int row = quad * 4 + r;
                float sl = 0.f, ql = 0.f;
                #pragma unroll
                for (int j = 0; j < 8; ++j) { sl += psum[row][j]; ql += psq[row][j]; }
                const float mu = sl * (1.0f / 256.0f);
                const float var = ql * (1.0f / 256.0f) - mu * mu;
                const float rstd = 1.0f / sqrtf(fmaxf(var, 0.f) + 1e-5f);
                #pragma unroll
                for (int ct = 0; ct < 2; ++ct) {
                    const int col = cb + ct * 16 + ln;
                    float o = (vv[ct][r] - mu) * rstd * ln2_g[l * 256 + col] + ln2_b[l * 256 + col];
                    avF[row][col] = o;
                    abuf[hsw_elem(row, col)] = f2bf(o);
                }
            }
        }
        __syncthreads();
    }

    // ==================== decoder + loss ====================
    {
        const unsigned short* W1 = Wm + (size_t)5 * 65536;
        f32x4 acc[2]; acc[0] = zero; acc[1] = zero;
        const unsigned short* wb = W1 + (size_t)(cb + ln) * 256 + quad * 8;
        #pragma unroll
        for (int ks = 0; ks < 8; ++ks) {
            bf16x8 A = *(const bf16x8*)&abuf[hsw_chunk(ln, ks, quad)];
            #pragma unroll
            for (int ct = 0; ct < 2; ++ct) {
                bf16x8 Bv = *(const bf16x8*)(wb + (size_t)ct * 16 * 256 + ks * 32);
                acc[ct] = __builtin_amdgcn_mfma_f32_16x16x32_bf16(A, Bv, acc[ct], 0, 0, 0);
            }
        }
        #pragma unroll
        for (int ct = 0; ct < 2; ++ct) {
            const int col = cb + ct * 16 + ln;
            const float bb = de_b1[col];
            #pragma unroll
            for (int r = 0; r < 4; ++r) {
                const int row = quad * 4 + r;
                hbuf[hsw_elem(row, col)] = f2bf(fmaxf(acc[ct][r] + bb, 0.f));
            }
        }
    }
    __syncthreads();

    {
        const unsigned short* W2 = Wm + (size_t)6 * 65536;
        f32x4 acc[2]; acc[0] = zero; acc[1] = zero;
        const unsigned short* wb = W2 + (size_t)(cb + ln) * 256 + quad * 8;
        #pragma unroll
        for (int ks = 0; ks < 8; ++ks) {
            bf16x8 A = *(const bf16x8*)&hbuf[hsw_chunk(ln, ks, quad)];
            #pragma unroll
            for (int ct = 0; ct < 2; ++ct) {
                bf16x8 Bv = *(const bf16x8*)(wb + (size_t)ct * 16 * 256 + ks * 32);
                acc[ct] = __builtin_amdgcn_mfma_f32_16x16x32_bf16(A, Bv, acc[ct], 0, 0, 0);
            }
        }
        __syncthreads();
        #pragma unroll
        for (int ct = 0; ct < 2; ++ct) {
            const int col = cb + ct * 16 + ln;
            const float bb = de_b2[col];
            #pragma unroll
            for (int r = 0; r < 4; ++r) {
                const int row = quad * 4 + r;
                hbuf[hsw_elem(row, col)] = f2bf(fmaxf(acc[ct][r] + bb, 0.f));
            }
        }
    }
    __syncthreads();

    {
        const unsigned short* W3 = Wm + (size_t)7 * 65536;
        const int cb3 = w * 16;
        f32x4 a3 = zero;
        const unsigned short* wb = W3 + (size_t)(cb3 + ln) * 256 + quad * 8;
        #pragma unroll
        for (int ks = 0; ks < 8; ++ks) {
            bf16x8 A = *(const bf16x8*)&hbuf[hsw_chunk(ln, ks, quad)];
            bf16x8 Bv = *(const bf16x8*)(wb + ks * 32);
            a3 = __builtin_amdgcn_mfma_f32_16x16x32_bf16(A, Bv, a3, 0, 0, 0);
        }
        float lg[4];
        const float bb = de_b3[cb3 + ln];
        #pragma unroll
        for (int r = 0; r < 4; ++r) lg[r] = a3[r] + bb;

        #pragma unroll
        for (int r = 0; r < 4; ++r) {
            float m = lg[r];
            #pragma unroll
            for (int off = 8; off >= 1; off >>= 1) m = fmaxf(m, __shfl_xor(m, off));
            if (ln == 0) psum[quad * 4 + r][w] = m;
        }
        __syncthreads();
        if (tid < 16) {
            float m = psum[tid][0];
            #pragma unroll
            for (int j = 1; j < 8; ++j) m = fmaxf(m, psum[tid][j]);
            rowmax[tid] = m;
            float tu = true_u[(size_t)b * Vc + pps[tid]];
            int t = (int)floorf(tu * 128.0f);
            tcol[tid] = t < 0 ? 0 : (t > 127 ? 127 : t);
        }
        __syncthreads();
        #pragma unroll
        for (int r = 0; r < 4; ++r) {
            const int row = quad * 4 + r;
            const float mx = rowmax[row];
            const int t = tcol[row];
            float e = expf(lg[r] - mx);
            float xt = ((cb3 + ln) == t) ? lg[r] : 0.f;
            #pragma unroll
            for (int off = 8; off >= 1; off >>= 1) {
                e += __shfl_xor(e, off);
                xt += __shfl_xor(xt, off);
            }
            if (ln == 0) { psum[row][w] = e; psq[row][w] = xt; }
        }
        __syncthreads();
        float contrib = 0.f;
        if (tid < 16) {
            float sum = 0.f, xt = 0.f;
            #pragma unroll
            for (int j = 0; j < 8; ++j) { sum += psum[tid][j]; xt += psq[tid][j]; }
            const float lp = logf(128.0f) + (xt - rowmax[tid]) - logf(sum);
            contrib = -lp;
        }
        if (w == 0) {
            #pragma unroll
            for (int off = 32; off >= 1; off >>= 1) contrib += __shfl_xor(contrib, off);
            if (lane == 0) atomicAdd(&outp[b], contrib);
        }
    }
}

// ---------------------------------------------------------------------------
extern "C" void kernel_launch(void* const* d_in, const int* in_sizes, int n_in,
                              void* d_out, int out_size, void* d_ws, size_t ws_size,
                              hipStream_t stream)
{
    (void)in_sizes; (void)n_in; (void)out_size; (void)ws_size;

    const float* encoded        = (const float*)d_in[0];
    const float* true_u         = (const float*)d_in[1];
    const float* attn_mask      = (const float*)d_in[2];
    const int*   pred_points    = (const int*)d_in[3];
    const int*   neighbor_index = (const int*)d_in[4];
    const float* kW1 = (const float*)d_in[5];
    const float* kb1 = (const float*)d_in[6];
    const float* kW2 = (const float*)d_in[7];
    const float* kb2 = (const float*)d_in[8];
    const float* kW3 = (const float*)d_in[9];
    const float* kb3 = (const float*)d_in[10];
    const float* vW1 = (const float*)d_in[11];
    const float* vb1 = (const float*)d_in[12];
    const float* vW2 = (const float*)d_in[13];
    const float* vb2 = (const float*)d_in[14];
    const float* vW3 = (const float*)d_in[15];
    const float* vb3 = (const float*)d_in[16];
    const float* ds_W  = (const float*)d_in[17];
    const float* ds_b  = (const float*)d_in[18];
    const float* ln1_g = (const float*)d_in[19];
    const float* ln1_b = (const float*)d_in[20];
    const float* ff_W1 = (const float*)d_in[21];
    const float* ff_b1 = (const float*)d_in[22];
    const float* ff_W2 = (const float*)d_in[23];
    const float* ff_b2 = (const float*)d_in[24];
    const float* ln2_g = (const float*)d_in[25];
    const float* ln2_b = (const float*)d_in[26];
    const float* de_W1 = (const float*)d_in[27];
    const float* de_b1 = (const float*)d_in[28];
    const float* de_W2 = (const float*)d_in[29];
    const float* de_b2 = (const float*)d_in[30];
    const float* de_W3 = (const float*)d_in[31];
    const float* de_b3 = (const float*)d_in[32];

    float* out = (float*)d_out;

    // workspace layout
    constexpr size_t KV_ELEMS = (size_t)Lc * Bc * Hc * Vc * 32;  // 8,388,608
    unsigned short* keys = (unsigned short*)d_ws;            // bf16 [l][b][v][256]
    unsigned short* vals = keys + KV_ELEMS;
    unsigned short* Xbf  = vals + KV_ELEMS;                  // 16384 x 256 bf16
    unsigned short* W1t  = Xbf + (size_t)ROWS_KV * 256;      // 32 nets x [256][256]
    unsigned short* W2t  = W1t + (size_t)32 * 65536;
    unsigned short* W3t  = W2t + (size_t)32 * 65536;         // 32 nets x [32][256]
    unsigned short* Wm   = W3t + (size_t)32 * 8192;          // 8 slots x 65536

    (void)hipMemsetAsync(out, 0, Bc * sizeof(float), stream);

    // prep
    conv_x_kernel<<<dim3(ROWS_KV * 256 / 4 / 256), 256, 0, stream>>>(encoded, Xbf);
    transpose_all_kernel<<<dim3(8, 8, 104), 256, 0, stream>>>(
        kW1, vW1, kW2, vW2, kW3, vW3,
        ds_W, ff_W1, ff_W2, de_W1, de_W2, de_W3,
        W1t, W2t, W3t, Wm);

    // KV MLPs v7b: 16 rg x 16 (l,h) x {k,v}
    kv_mfma_kernel<<<dim3(16, 16, 2), 512, 0, stream>>>(
        Xbf, true_u, W1t, W2t, W3t, kW1, vW1,
        kb1, kb2, kb3, vb1, vb2, vb3, keys, vals);

    // fused tail: 256 blocks x 16 rows (R16 shape, ILP-interleaved attention)
    decoder_kernel<<<dim3(ROWS_AT / 16), 512, 0, stream>>>(
        Xbf, true_u, keys, vals, neighbor_index, attn_mask, pred_points, Wm,
        ds_b, ln1_g, ln1_b, ff_b1, ff_b2, ln2_g, ln2_b,
        de_b1, de_b2, de_b3, out);
}

// Round 20
// 447.243 us; speedup vs baseline: 1.0815x; 1.0104x over previous
//
#include <hip/hip_runtime.h>
#include <hip/hip_bf16.h>
#include <cstdint>
#include <cstddef>

// Problem dims (compile-time)
constexpr int Bc = 8;
constexpr int Vc = 2048;   // S*T
constexpr int Pc = 512;
constexpr int Hc = 8;
constexpr int Lc = 2;
constexpr int ROWS_KV = Bc * Vc;   // 16384
constexpr int ROWS_AT = Bc * Pc;   // 4096

typedef __attribute__((ext_vector_type(8))) short bf16x8;   // 8 bf16 (4 VGPRs)
typedef __attribute__((ext_vector_type(4))) float f32x4;

static __device__ __forceinline__ unsigned short f2bf(float v) {
    __hip_bfloat16 h = __float2bfloat16(v);
    return *(unsigned short*)&h;
}
static __device__ __forceinline__ float bflo(unsigned int u) {
    return __uint_as_float(u << 16);
}
static __device__ __forceinline__ float bfhi(unsigned int u) {
    return __uint_as_float(u & 0xffff0000u);
}

// ---------------------------------------------------------------------------
// Merged prep: weight transposes [K x C] fp32 -> [C x 256] bf16, plus
// encoded fp32 -> bf16 conversion on z >= 104.
// z: 0..31 W1, 32..63 W2, 64..95 W3 (C=32), 96..103 misc, 104..167 conv X
// (64 slices x 64 blocks x 256 thr x float4 = 16384x256 floats exactly).
// ---------------------------------------------------------------------------
__global__ __launch_bounds__(256) void prep_all_kernel(
    const float* kW1, const float* vW1, const float* kW2, const float* vW2,
    const float* kW3, const float* vW3,
    const float* ds_W, const float* ff_W1, const float* ff_W2,
    const float* de_W1, const float* de_W2, const float* de_W3,
    const float* encoded,
    unsigned short* __restrict__ W1t, unsigned short* __restrict__ W2t,
    unsigned short* __restrict__ W3t, unsigned short* __restrict__ Wm,
    unsigned short* __restrict__ Xbf)
{
    const int z = blockIdx.z;
    if (z >= 104) {
        const int idx = (z - 104) * 64 + blockIdx.y * 8 + blockIdx.x;
        if (idx >= 4096) return;                 // 4096 * 256 float4 = full X
        const int i = idx * 256 + threadIdx.x;   // float4 index
        float4 v = ((const float4*)encoded)[i];
        ushort4 o;
        o.x = f2bf(v.x); o.y = f2bf(v.y); o.z = f2bf(v.z); o.w = f2bf(v.w);
        ((ushort4*)Xbf)[i] = o;
        return;
    }
    const float* src;
    unsigned short* dst;
    int C;
    if (z < 32) {
        const int net = z;
        src = ((net >> 4) ? vW1 : kW1) + (size_t)(net & 15) * 257 * 256;
        dst = W1t + (size_t)net * 65536;
        C = 256;
    } else if (z < 64) {
        const int net = z - 32;
        src = ((net >> 4) ? vW2 : kW2) + (size_t)(net & 15) * 256 * 256;
        dst = W2t + (size_t)net * 65536;
        C = 256;
    } else if (z < 96) {
        const int net = z - 64;
        src = ((net >> 4) ? vW3 : kW3) + (size_t)(net & 15) * 256 * 32;
        dst = W3t + (size_t)net * 8192;
        C = 32;
    } else {
        const int id = z - 96;
        const float* srcs[8] = {ds_W, ff_W1, ff_W1 + (size_t)65536,
                                ff_W2, ff_W2 + (size_t)65536, de_W1, de_W2, de_W3};
        src = srcs[id];
        dst = Wm + (size_t)id * 65536;
        C = (id == 7) ? 128 : 256;
    }
    if (blockIdx.x * 32 >= C) return;
    __shared__ float t[32][33];
    const int c0 = blockIdx.x * 32, k0 = blockIdx.y * 32;
    const int tx = threadIdx.x & 31, ty = threadIdx.x >> 5;
    #pragma unroll
    for (int i = 0; i < 32; i += 8)
        t[ty + i][tx] = src[(size_t)(k0 + ty + i) * C + (c0 + tx)];
    __syncthreads();
    #pragma unroll
    for (int i = 0; i < 32; i += 8)
        dst[(size_t)(c0 + ty + i) * 256 + (k0 + tx)] = f2bf(t[tx][ty + i]);
}

// h-buf XOR swizzle: rows x 256 shorts (32 chunks of 8 shorts).
static __device__ __forceinline__ int hsw_chunk(int row, int ks, int quad) {
    int c = ks * 4 + quad;
    int p = c ^ (row & 31);
    return row * 256 + p * 8;
}
static __device__ __forceinline__ int hsw_elem(int row, int col) {
    int p = (col >> 3) ^ (row & 31);
    return row * 256 + p * 8 + (col & 7);
}

// ---------------------------------------------------------------------------
// Fused 3-layer KV MLP — v7b (best measured): weight-resident W1/W2 in
// registers, W3 in 16KB swizzled LDS, 8 waves, 512 blocks.
// Output bf16 [l][b][v][h*32].
// ---------------------------------------------------------------------------
__global__ __launch_bounds__(512, 2) void kv_mfma_kernel(
    const unsigned short* __restrict__ Xbf, const float* __restrict__ true_u,
    const unsigned short* __restrict__ W1t, const unsigned short* __restrict__ W2t,
    const unsigned short* __restrict__ W3t,
    const float* __restrict__ kW1, const float* __restrict__ vW1,
    const float* __restrict__ kb1, const float* __restrict__ kb2, const float* __restrict__ kb3,
    const float* __restrict__ vb1, const float* __restrict__ vb2, const float* __restrict__ vb3,
    unsigned short* __restrict__ keys, unsigned short* __restrict__ vals)
{
    __shared__ unsigned short hbuf[64 * 256];    // 32 KB: X -> h1 -> h2 (swizzled)
    __shared__ unsigned short w3buf[32 * 256];   // 16 KB: W3 slice (swizzled)
    __shared__ float tub[64];                    // true_u tile

    const int tid = threadIdx.x;
    const int w = tid >> 6, lane = tid & 63;
    const int ln = lane & 15, quad = lane >> 4;
    const int lh = blockIdx.y, isv = blockIdx.z;
    const int net = isv * 16 + lh;
    const float* W1f = (isv ? vW1 : kW1) + (size_t)lh * 257 * 256;
    const float* b1  = (isv ? vb1 : kb1) + lh * 256;
    const float* b2  = (isv ? vb2 : kb2) + lh * 256;
    const float* b3  = (isv ? vb3 : kb3) + lh * 32;
    const unsigned short* w1 = W1t + (size_t)net * 65536;
    const unsigned short* w2 = W2t + (size_t)net * 65536;
    const unsigned short* w3 = W3t + (size_t)net * 8192;
    unsigned short* outp = isv ? vals : keys;
    const int base = blockIdx.x * 1024;          // row-group (16 tiles)
    const int cb = w * 32;                       // wave's column base (stages 1-2)

    // ---- one-time: W1/W2 column slices -> registers ----
    bf16x8 B1[16], B2[16];
    {
        const unsigned short* p1 = w1 + (size_t)(cb + ln) * 256 + quad * 8;
        const unsigned short* p2 = w2 + (size_t)(cb + ln) * 256 + quad * 8;
        #pragma unroll
        for (int ks = 0; ks < 8; ++ks)
            #pragma unroll
            for (int ct = 0; ct < 2; ++ct) {
                B1[ks * 2 + ct] = *(const bf16x8*)(p1 + (size_t)ct * 16 * 256 + ks * 32);
                B2[ks * 2 + ct] = *(const bf16x8*)(p2 + (size_t)ct * 16 * 256 + ks * 32);
            }
    }
    // ---- one-time: W3 -> swizzled LDS ----
    {
        #pragma unroll
        for (int j = 0; j < 2; ++j) {
            const int cidx = tid * 2 + j;
            const int col = cidx >> 5, c = cidx & 31;
            uint4 d = *(const uint4*)(w3 + cidx * 8);
            *(uint4*)&w3buf[col * 256 + (c ^ (col & 31)) * 8] = d;
        }
    }
    float w1f[2], b1v[2], b2v[2];
    #pragma unroll
    for (int ct = 0; ct < 2; ++ct) {
        const int col = cb + ct * 16 + ln;
        w1f[ct] = W1f[256 * 256 + col];
        b1v[ct] = b1[col];
        b2v[ct] = b2[col];
    }
    const int rt3 = w & 3, ct3 = w >> 2;
    const float b3v = b3[ct3 * 16 + ln];

    const int b_ = base >> 11;
    const int l_ = lh >> 3, h_ = lh & 7;
    unsigned short* ob = outp + (((size_t)l_ * Bc + b_) * Vc) * 256 + h_ * 32;

    const f32x4 zero = {0.f, 0.f, 0.f, 0.f};
    const int xr = tid >> 3, cg = tid & 7;

    for (int t = 0; t < 16; ++t) {
        const int row0 = base + t * 64;
        __syncthreads();

        {
            const unsigned short* gx = Xbf + (size_t)(row0 + xr) * 256;
            #pragma unroll
            for (int j = 0; j < 4; ++j) {
                const int c = j * 8 + cg;
                uint4 d = *(const uint4*)(gx + c * 8);
                *(uint4*)&hbuf[xr * 256 + (c ^ (xr & 31)) * 8] = d;
            }
            if (tid < 64) tub[tid] = true_u[row0 + tid];
        }
        __syncthreads();

        // ---- stage 1 ----
        f32x4 acc[4][2];
        #pragma unroll
        for (int rt = 0; rt < 4; ++rt)
            #pragma unroll
            for (int ct = 0; ct < 2; ++ct) acc[rt][ct] = zero;
        #pragma unroll
        for (int ks = 0; ks < 8; ++ks) {
            bf16x8 A[4];
            #pragma unroll
            for (int rt = 0; rt < 4; ++rt)
                A[rt] = *(const bf16x8*)&hbuf[hsw_chunk(rt * 16 + ln, ks, quad)];
            #pragma unroll
            for (int rt = 0; rt < 4; ++rt)
                #pragma unroll
                for (int ct = 0; ct < 2; ++ct)
                    acc[rt][ct] = __builtin_amdgcn_mfma_f32_16x16x32_bf16(A[rt], B1[ks * 2 + ct], acc[rt][ct], 0, 0, 0);
        }
        __syncthreads();
        #pragma unroll
        for (int ct = 0; ct < 2; ++ct) {
            const int col = cb + ct * 16 + ln;
            #pragma unroll
            for (int rt = 0; rt < 4; ++rt)
                #pragma unroll
                for (int r = 0; r < 4; ++r) {
                    const int row = rt * 16 + quad * 4 + r;
                    float v = fmaxf(acc[rt][ct][r] + b1v[ct] + tub[row] * w1f[ct], 0.f);
                    hbuf[hsw_elem(row, col)] = f2bf(v);
                }
        }
        __syncthreads();

        // ---- stage 2 ----
        #pragma unroll
        for (int rt = 0; rt < 4; ++rt)
            #pragma unroll
            for (int ct = 0; ct < 2; ++ct) acc[rt][ct] = zero;
        #pragma unroll
        for (int ks = 0; ks < 8; ++ks) {
            bf16x8 A[4];
            #pragma unroll
            for (int rt = 0; rt < 4; ++rt)
                A[rt] = *(const bf16x8*)&hbuf[hsw_chunk(rt * 16 + ln, ks, quad)];
            #pragma unroll
            for (int rt = 0; rt < 4; ++rt)
                #pragma unroll
                for (int ct = 0; ct < 2; ++ct)
                    acc[rt][ct] = __builtin_amdgcn_mfma_f32_16x16x32_bf16(A[rt], B2[ks * 2 + ct], acc[rt][ct], 0, 0, 0);
        }
        __syncthreads();
        #pragma unroll
        for (int ct = 0; ct < 2; ++ct) {
            const int col = cb + ct * 16 + ln;
            #pragma unroll
            for (int rt = 0; rt < 4; ++rt)
                #pragma unroll
                for (int r = 0; r < 4; ++r) {
                    const int row = rt * 16 + quad * 4 + r;
                    hbuf[hsw_elem(row, col)] = f2bf(fmaxf(acc[rt][ct][r] + b2v[ct], 0.f));
                }
        }
        __syncthreads();

        // ---- stage 3 ----
        f32x4 acc3 = zero;
        #pragma unroll
        for (int ks = 0; ks < 8; ++ks) {
            bf16x8 A  = *(const bf16x8*)&hbuf[hsw_chunk(rt3 * 16 + ln, ks, quad)];
            bf16x8 Bv = *(const bf16x8*)&w3buf[hsw_chunk(ct3 * 16 + ln, ks, quad)];
            acc3 = __builtin_amdgcn_mfma_f32_16x16x32_bf16(A, Bv, acc3, 0, 0, 0);
        }
        #pragma unroll
        for (int r = 0; r < 4; ++r) {
            const int grow = row0 + rt3 * 16 + quad * 4 + r;
            ob[(size_t)(grow & 2047) * 256 + ct3 * 16 + ln] = f2bf(acc3[r] + b3v);
        }
    }
}

// ---------------------------------------------------------------------------
// FUSED TAIL (R18 + V-preload): per block = 16 rows, 256 blocks, 512 threads.
// Attention: wave w owns rows w*2/w*2+1 interleaved; V tiles preloaded at
// the top of each head iteration so V-gather latency overlaps score+softmax.
// ---------------------------------------------------------------------------
__global__ __launch_bounds__(512) void decoder_kernel(
    const unsigned short* __restrict__ Xbf, const float* __restrict__ true_u,
    const unsigned short* __restrict__ keys, const unsigned short* __restrict__ vals,
    const int* __restrict__ nbr, const float* __restrict__ mask,
    const int* __restrict__ pp, const unsigned short* __restrict__ Wm,
    const float* __restrict__ ds_b,
    const float* __restrict__ ln1_g, const float* __restrict__ ln1_b,
    const float* __restrict__ ff_b1, const float* __restrict__ ff_b2,
    const float* __restrict__ ln2_g, const float* __restrict__ ln2_b,
    const float* __restrict__ de_b1, const float* __restrict__ de_b2,
    const float* __restrict__ de_b3, float* __restrict__ outp)
{
    __shared__ float avF[16][264];
    __shared__ float attF[16][264];
    __shared__ unsigned short abuf[16 * 256];
    __shared__ unsigned short hbuf[16 * 256];
    __shared__ int   ni_s[16][64];
    __shared__ float wtsb[16][64];
    __shared__ float psum[16][8], psq[16][8];
    __shared__ float rowmax[16];
    __shared__ int   tcol[16];
    __shared__ int   pps[16];

    const int tid = threadIdx.x;
    const int w = tid >> 6, lane = tid & 63;
    const int ln = lane & 15, quad = lane >> 4;
    const int bid = blockIdx.x;
    const int b = bid & 7;                       // XCD-affine batch
    const int r0 = b * 512 + (bid >> 3) * 16;    // global row base
    const int cb = w * 32;                       // GEMM column base

    const f32x4 zero = {0.f, 0.f, 0.f, 0.f};

    // ---- init: pp values + neighbor indices ----
    if (tid < 16) pps[tid] = pp[(r0 + tid) & 511];
    #pragma unroll
    for (int j = 0; j < 2; ++j) {
        const int idx = tid * 2 + j;             // 1024 = 16*64
        const int row = idx >> 6, n = idx & 63;
        ni_s[row][n] = nbr[((r0 + row) & 511) * 64 + n];
    }
    __syncthreads();

    // ---- gather X rows into abuf ----
    {
        const int row = tid >> 5, c = tid & 31;
        const size_t arow = (size_t)b * Vc + pps[row];
        uint4 d = *(const uint4*)(Xbf + arow * 256 + c * 8);
        *(uint4*)&abuf[row * 256 + ((c ^ row) * 8)] = d;
    }
    __syncthreads();

    // ---- ds GEMM ----
    {
        const unsigned short* Wt = Wm;
        f32x4 acc[2]; acc[0] = zero; acc[1] = zero;
        const unsigned short* wb = Wt + (size_t)(cb + ln) * 256 + quad * 8;
        #pragma unroll
        for (int ks = 0; ks < 8; ++ks) {
            bf16x8 A = *(const bf16x8*)&abuf[hsw_chunk(ln, ks, quad)];
            #pragma unroll
            for (int ct = 0; ct < 2; ++ct) {
                bf16x8 Bv = *(const bf16x8*)(wb + (size_t)ct * 16 * 256 + ks * 32);
                acc[ct] = __builtin_amdgcn_mfma_f32_16x16x32_bf16(A, Bv, acc[ct], 0, 0, 0);
            }
        }
        __syncthreads();
        #pragma unroll
        for (int ct = 0; ct < 2; ++ct) {
            const int col = cb + ct * 16 + ln;
            const float bb = ds_b[col];
            #pragma unroll
            for (int r = 0; r < 4; ++r) {
                const int row = quad * 4 + r;
                float v = acc[ct][r] + bb;
                avF[row][col] = v;
                abuf[hsw_elem(row, col)] = f2bf(v);
            }
        }
    }
    __syncthreads();

    // ==================== transformer layers ====================
    for (int l = 0; l < Lc; ++l) {
        const unsigned short* kvb = keys + (((size_t)l * Bc + b) * Vc) * 256;
        const unsigned short* vvb = vals + (((size_t)l * Bc + b) * Vc) * 256;

        // ---- attention: rows w*2 and w*2+1 interleaved, V preloaded ----
        {
            const int row0a = w * 2, row1a = w * 2 + 1;
            const int p0 = (r0 + row0a) & 511, p1 = (r0 + row1a) & 511;
            const int n = lane;
            const int vi0 = ni_s[row0a][n], vi1 = ni_s[row1a][n];
            const float m0 = mask[p0 * 64 + n], m1 = mask[p1 * 64 + n];
            const int nb4 = n >> 2, cg8 = (n & 3) * 8;
            int vrow0[4], vrow1[4];
            #pragma unroll
            for (int pass = 0; pass < 4; ++pass) {
                const int nn = pass * 16 + nb4;
                vrow0[pass] = ni_s[row0a][nn];
                vrow1[pass] = ni_s[row1a][nn];
            }
            for (int h = 0; h < 8; ++h) {
                // V preload (independent of softmax -> overlaps score+softmax)
                uint4 vu0[4], vu1[4];
                #pragma unroll
                for (int pass = 0; pass < 4; ++pass) {
                    vu0[pass] = *(const uint4*)(vvb + (size_t)vrow0[pass] * 256 + h * 32 + cg8);
                    vu1[pass] = *(const uint4*)(vvb + (size_t)vrow1[pass] * 256 + h * 32 + cg8);
                }
                // q for both rows (broadcast LDS reads)
                float q0[32], q1[32];
                #pragma unroll
                for (int j = 0; j < 8; ++j) {
                    float4 t0 = *(const float4*)&avF[row0a][h * 32 + j * 4];
                    float4 t1 = *(const float4*)&avF[row1a][h * 32 + j * 4];
                    q0[j * 4 + 0] = t0.x; q0[j * 4 + 1] = t0.y;
                    q0[j * 4 + 2] = t0.z; q0[j * 4 + 3] = t0.w;
                    q1[j * 4 + 0] = t1.x; q1[j * 4 + 1] = t1.y;
                    q1[j * 4 + 2] = t1.z; q1[j * 4 + 3] = t1.w;
                }
                // two independent score chains
                const unsigned short* kp0 = kvb + (size_t)vi0 * 256 + h * 32;
                const unsigned short* kp1 = kvb + (size_t)vi1 * 256 + h * 32;
                float s0 = 0.f, s1 = 0.f;
                #pragma unroll
                for (int j = 0; j < 4; ++j) {
                    uint4 u0 = *(const uint4*)(kp0 + j * 8);
                    uint4 u1 = *(const uint4*)(kp1 + j * 8);
                    s0 += q0[j * 8 + 0] * bflo(u0.x) + q0[j * 8 + 1] * bfhi(u0.x);
                    s1 += q1[j * 8 + 0] * bflo(u1.x) + q1[j * 8 + 1] * bfhi(u1.x);
                    s0 += q0[j * 8 + 2] * bflo(u0.y) + q0[j * 8 + 3] * bfhi(u0.y);
                    s1 += q1[j * 8 + 2] * bflo(u1.y) + q1[j * 8 + 3] * bfhi(u1.y);
                    s0 += q0[j * 8 + 4] * bflo(u0.z) + q0[j * 8 + 5] * bfhi(u0.z);
                    s1 += q1[j * 8 + 4] * bflo(u1.z) + q1[j * 8 + 5] * bfhi(u1.z);
                    s0 += q0[j * 8 + 6] * bflo(u0.w) + q0[j * 8 + 7] * bfhi(u0.w);
                    s1 += q1[j * 8 + 6] * bflo(u1.w) + q1[j * 8 + 7] * bfhi(u1.w);
                }
                s0 = (s0 - m0) * 0.17677669529663689f;
                s1 = (s1 - m1) * 0.17677669529663689f;
                // interleaved softmax butterflies
                float mx0 = s0, mx1 = s1;
                #pragma unroll
                for (int off = 32; off >= 1; off >>= 1) {
                    mx0 = fmaxf(mx0, __shfl_xor(mx0, off));
                    mx1 = fmaxf(mx1, __shfl_xor(mx1, off));
                }
                float e0 = expf(s0 - mx0), e1 = expf(s1 - mx1);
                float sum0 = e0, sum1 = e1;
                #pragma unroll
                for (int off = 32; off >= 1; off >>= 1) {
                    sum0 += __shfl_xor(sum0, off);
                    sum1 += __shfl_xor(sum1, off);
                }
                wtsb[row0a][n] = e0 / sum0;
                wtsb[row1a][n] = e1 / sum1;
                // PV with preloaded V
                float a0[8], a1[8];
                #pragma unroll
                for (int j = 0; j < 8; ++j) { a0[j] = 0.f; a1[j] = 0.f; }
                #pragma unroll
                for (int pass = 0; pass < 4; ++pass) {
                    const int nn = pass * 16 + nb4;
                    const float w0 = wtsb[row0a][nn], w1 = wtsb[row1a][nn];
                    uint4 u0 = vu0[pass];
                    uint4 u1 = vu1[pass];
                    a0[0] += w0 * bflo(u0.x); a0[1] += w0 * bfhi(u0.x);
                    a1[0] += w1 * bflo(u1.x); a1[1] += w1 * bfhi(u1.x);
                    a0[2] += w0 * bflo(u0.y); a0[3] += w0 * bfhi(u0.y);
                    a1[2] += w1 * bflo(u1.y); a1[3] += w1 * bfhi(u1.y);
                    a0[4] += w0 * bflo(u0.z); a0[5] += w0 * bfhi(u0.z);
                    a1[4] += w1 * bflo(u1.z); a1[5] += w1 * bfhi(u1.z);
                    a0[6] += w0 * bflo(u0.w); a0[7] += w0 * bfhi(u0.w);
                    a1[6] += w1 * bflo(u1.w); a1[7] += w1 * bfhi(u1.w);
                }
                #pragma unroll
                for (int off = 4; off <= 32; off <<= 1)
                    #pragma unroll
                    for (int j = 0; j < 8; ++j) {
                        a0[j] += __shfl_xor(a0[j], off);
                        a1[j] += __shfl_xor(a1[j], off);
                    }
                if (nb4 == 0)
                    #pragma unroll
                    for (int j = 0; j < 8; ++j) {
                        attF[row0a][h * 32 + cg8 + j] = a0[j];
                        attF[row1a][h * 32 + cg8 + j] = a1[j];
                    }
            }
            // LN1 for both rows (in-wave)
            #pragma unroll
            for (int rr = 0; rr < 2; ++rr) {
                const int row = w * 2 + rr;
                const int c0 = lane * 4;
                float x[4];
                float sl = 0.f, ql = 0.f;
                #pragma unroll
                for (int j = 0; j < 4; ++j) {
                    x[j] = avF[row][c0 + j] + attF[row][c0 + j];
                    sl += x[j]; ql += x[j] * x[j];
                }
                #pragma unroll
                for (int off = 32; off >= 1; off >>= 1) {
                    sl += __shfl_xor(sl, off);
                    ql += __shfl_xor(ql, off);
                }
                const float mu = sl * (1.0f / 256.0f);
                const float var = ql * (1.0f / 256.0f) - mu * mu;
                const float rstd = 1.0f / sqrtf(fmaxf(var, 0.f) + 1e-5f);
                #pragma unroll
                for (int j = 0; j < 4; ++j) {
                    const int col = c0 + j;
                    float o = (x[j] - mu) * rstd * ln1_g[l * 256 + col] + ln1_b[l * 256 + col];
                    avF[row][col] = o;
                    abuf[hsw_elem(row, col)] = f2bf(o);
                }
            }
        }
        __syncthreads();

        // ---- ff stage A: T1 = relu(abuf @ W1 + b1) -> hbuf ----
        {
            const unsigned short* W1 = Wm + (size_t)(1 + l) * 65536;
            f32x4 acc[2]; acc[0] = zero; acc[1] = zero;
            const unsigned short* wb = W1 + (size_t)(cb + ln) * 256 + quad * 8;
            #pragma unroll
            for (int ks = 0; ks < 8; ++ks) {
                bf16x8 A = *(const bf16x8*)&abuf[hsw_chunk(ln, ks, quad)];
                #pragma unroll
                for (int ct = 0; ct < 2; ++ct) {
                    bf16x8 Bv = *(const bf16x8*)(wb + (size_t)ct * 16 * 256 + ks * 32);
                    acc[ct] = __builtin_amdgcn_mfma_f32_16x16x32_bf16(A, Bv, acc[ct], 0, 0, 0);
                }
            }
            #pragma unroll
            for (int ct = 0; ct < 2; ++ct) {
                const int col = cb + ct * 16 + ln;
                const float bb = ff_b1[l * 256 + col];
                #pragma unroll
                for (int r = 0; r < 4; ++r) {
                    const int row = quad * 4 + r;
                    hbuf[hsw_elem(row, col)] = f2bf(fmaxf(acc[ct][r] + bb, 0.f));
                }
            }
        }
        __syncthreads();

        // ---- ff stage B + residual + LN2 ----
        {
            const unsigned short* W2 = Wm + (size_t)(3 + l) * 65536;
            f32x4 acc[2]; acc[0] = zero; acc[1] = zero;
            const unsigned short* wb = W2 + (size_t)(cb + ln) * 256 + quad * 8;
            #pragma unroll
            for (int ks = 0; ks < 8; ++ks) {
                bf16x8 A = *(const bf16x8*)&hbuf[hsw_chunk(ln, ks, quad)];
                #pragma unroll
                for (int ct = 0; ct < 2; ++ct) {
                    bf16x8 Bv = *(const bf16x8*)(wb + (size_t)ct * 16 * 256 + ks * 32);
                    acc[ct] = __builtin_amdgcn_mfma_f32_16x16x32_bf16(A, Bv, acc[ct], 0, 0, 0);
                }
            }
            float vv[2][4];
            #pragma unroll
            for (int ct = 0; ct < 2; ++ct) {
                const int col = cb + ct * 16 + ln;
                const float bb = ff_b2[l * 256 + col];
                #pragma unroll
                for (int r = 0; r < 4; ++r) {
                    const int row = quad * 4 + r;
                    vv[ct][r] = acc[ct][r] + bb + avF[row][col];
                }
            }
            #pragma unroll
            for (int r = 0; r < 4; ++r) {
                float sl = vv[0][r] + vv[1][r];
                float ql = vv[0][r] * vv[0][r] + vv[1][r] * vv[1][r];
                #pragma unroll
                for (int off = 8; off >= 1; off >>= 1) {
                    sl += __shfl_xor(sl, off);
                    ql += __shfl_xor(ql, off);
                }
                if (ln == 0) {
                    const int row = quad * 4 + r;
                    psum[row][w] = sl; psq[row][w] = ql;
                }
            }
            __syncthreads();
            #pragma unroll
            for (int r = 0; r < 4; ++r) {
                const int row = quad * 4 + r;
                float sl = 0.f, ql = 0.f;
                #pragma unroll
                for (int j = 0; j < 8; ++j) { sl += psum[row][j]; ql += psq[row][j]; }
                const float mu = sl * (1.0f / 256.0f);
                const float var = ql * (1.0f / 256.0f) - mu * mu;
                const float rstd = 1.0f / sqrtf(fmaxf(var, 0.f) + 1e-5f);
                #pragma unroll
                for (int ct = 0; ct < 2; ++ct) {
                    const int col = cb + ct * 16 + ln;
                    float o = (vv[ct][r] - mu) * rstd * ln2_g[l * 256 + col] + ln2_b[l * 256 + col];
                    avF[row][col] = o;
                    abuf[hsw_elem(row, col)] = f2bf(o);
                }
            }
        }
        __syncthreads();
    }

    // ==================== decoder + loss ====================
    {
        const unsigned short* W1 = Wm + (size_t)5 * 65536;
        f32x4 acc[2]; acc[0] = zero; acc[1] = zero;
        const unsigned short* wb = W1 + (size_t)(cb + ln) * 256 + quad * 8;
        #pragma unroll
        for (int ks = 0; ks < 8; ++ks) {
            bf16x8 A = *(const bf16x8*)&abuf[hsw_chunk(ln, ks, quad)];
            #pragma unroll
            for (int ct = 0; ct < 2; ++ct) {
                bf16x8 Bv = *(const bf16x8*)(wb + (size_t)ct * 16 * 256 + ks * 32);
                acc[ct] = __builtin_amdgcn_mfma_f32_16x16x32_bf16(A, Bv, acc[ct], 0, 0, 0);
            }
        }
        #pragma unroll
        for (int ct = 0; ct < 2; ++ct) {
            const int col = cb + ct * 16 + ln;
            const float bb = de_b1[col];
            #pragma unroll
            for (int r = 0; r < 4; ++r) {
                const int row = quad * 4 + r;
                hbuf[hsw_elem(row, col)] = f2bf(fmaxf(acc[ct][r] + bb, 0.f));
            }
        }
    }
    __syncthreads();

    {
        const unsigned short* W2 = Wm + (size_t)6 * 65536;
        f32x4 acc[2]; acc[0] = zero; acc[1] = zero;
        const unsigned short* wb = W2 + (size_t)(cb + ln) * 256 + quad * 8;
        #pragma unroll
        for (int ks = 0; ks < 8; ++ks) {
            bf16x8 A = *(const bf16x8*)&hbuf[hsw_chunk(ln, ks, quad)];
            #pragma unroll
            for (int ct = 0; ct < 2; ++ct) {
                bf16x8 Bv = *(const bf16x8*)(wb + (size_t)ct * 16 * 256 + ks * 32);
                acc[ct] = __builtin_amdgcn_mfma_f32_16x16x32_bf16(A, Bv, acc[ct], 0, 0, 0);
            }
        }
        __syncthreads();
        #pragma unroll
        for (int ct = 0; ct < 2; ++ct) {
            const int col = cb + ct * 16 + ln;
            const float bb = de_b2[col];
            #pragma unroll
            for (int r = 0; r < 4; ++r) {
                const int row = quad * 4 + r;
                hbuf[hsw_elem(row, col)] = f2bf(fmaxf(acc[ct][r] + bb, 0.f));
            }
        }
    }
    __syncthreads();

    {
        const unsigned short* W3 = Wm + (size_t)7 * 65536;
        const int cb3 = w * 16;
        f32x4 a3 = zero;
        const unsigned short* wb = W3 + (size_t)(cb3 + ln) * 256 + quad * 8;
        #pragma unroll
        for (int ks = 0; ks < 8; ++ks) {
            bf16x8 A = *(const bf16x8*)&hbuf[hsw_chunk(ln, ks, quad)];
            bf16x8 Bv = *(const bf16x8*)(wb + ks * 32);
            a3 = __builtin_amdgcn_mfma_f32_16x16x32_bf16(A, Bv, a3, 0, 0, 0);
        }
        float lg[4];
        const float bb = de_b3[cb3 + ln];
        #pragma unroll
        for (int r = 0; r < 4; ++r) lg[r] = a3[r] + bb;

        #pragma unroll
        for (int r = 0; r < 4; ++r) {
            float m = lg[r];
            #pragma unroll
            for (int off = 8; off >= 1; off >>= 1) m = fmaxf(m, __shfl_xor(m, off));
            if (ln == 0) psum[quad * 4 + r][w] = m;
        }
        __syncthreads();
        if (tid < 16) {
            float m = psum[tid][0];
            #pragma unroll
            for (int j = 1; j < 8; ++j) m = fmaxf(m, psum[tid][j]);
            rowmax[tid] = m;
            float tu = true_u[(size_t)b * Vc + pps[tid]];
            int t = (int)floorf(tu * 128.0f);
            tcol[tid] = t < 0 ? 0 : (t > 127 ? 127 : t);
        }
        __syncthreads();
        #pragma unroll
        for (int r = 0; r < 4; ++r) {
            const int row = quad * 4 + r;
            const float mx = rowmax[row];
            const int t = tcol[row];
            float e = expf(lg[r] - mx);
            float xt = ((cb3 + ln) == t) ? lg[r] : 0.f;
            #pragma unroll
            for (int off = 8; off >= 1; off >>= 1) {
                e += __shfl_xor(e, off);
                xt += __shfl_xor(xt, off);
            }
            if (ln == 0) { psum[row][w] = e; psq[row][w] = xt; }
        }
        __syncthreads();
        float contrib = 0.f;
        if (tid < 16) {
            float sum = 0.f, xt = 0.f;
            #pragma unroll
            for (int j = 0; j < 8; ++j) { sum += psum[tid][j]; xt += psq[tid][j]; }
            const float lp = logf(128.0f) + (xt - rowmax[tid]) - logf(sum);
            contrib = -lp;
        }
        if (w == 0) {
            #pragma unroll
            for (int off = 32; off >= 1; off >>= 1) contrib += __shfl_xor(contrib, off);
            if (lane == 0) atomicAdd(&outp[b], contrib);
        }
    }
}

// ---------------------------------------------------------------------------
extern "C" void kernel_launch(void* const* d_in, const int* in_sizes, int n_in,
                              void* d_out, int out_size, void* d_ws, size_t ws_size,
                              hipStream_t stream)
{
    (void)in_sizes; (void)n_in; (void)out_size; (void)ws_size;

    const float* encoded        = (const float*)d_in[0];
    const float* true_u         = (const float*)d_in[1];
    const float* attn_mask      = (const float*)d_in[2];
    const int*   pred_points    = (const int*)d_in[3];
    const int*   neighbor_index = (const int*)d_in[4];
    const float* kW1 = (const float*)d_in[5];
    const float* kb1 = (const float*)d_in[6];
    const float* kW2 = (const float*)d_in[7];
    const float* kb2 = (const float*)d_in[8];
    const float* kW3 = (const float*)d_in[9];
    const float* kb3 = (const float*)d_in[10];
    const float* vW1 = (const float*)d_in[11];
    const float* vb1 = (const float*)d_in[12];
    const float* vW2 = (const float*)d_in[13];
    const float* vb2 = (const float*)d_in[14];
    const float* vW3 = (const float*)d_in[15];
    const float* vb3 = (const float*)d_in[16];
    const float* ds_W  = (const float*)d_in[17];
    const float* ds_b  = (const float*)d_in[18];
    const float* ln1_g = (const float*)d_in[19];
    const float* ln1_b = (const float*)d_in[20];
    const float* ff_W1 = (const float*)d_in[21];
    const float* ff_b1 = (const float*)d_in[22];
    const float* ff_W2 = (const float*)d_in[23];
    const float* ff_b2 = (const float*)d_in[24];
    const float* ln2_g = (const float*)d_in[25];
    const float* ln2_b = (const float*)d_in[26];
    const float* de_W1 = (const float*)d_in[27];
    const float* de_b1 = (const float*)d_in[28];
    const float* de_W2 = (const float*)d_in[29];
    const float* de_b2 = (const float*)d_in[30];
    const float* de_W3 = (const float*)d_in[31];
    const float* de_b3 = (const float*)d_in[32];

    float* out = (float*)d_out;

    // workspace layout
    constexpr size_t KV_ELEMS = (size_t)Lc * Bc * Hc * Vc * 32;  // 8,388,608
    unsigned short* keys = (unsigned short*)d_ws;            // bf16 [l][b][v][256]
    unsigned short* vals = keys + KV_ELEMS;
    unsigned short* Xbf  = vals + KV_ELEMS;                  // 16384 x 256 bf16
    unsigned short* W1t  = Xbf + (size_t)ROWS_KV * 256;      // 32 nets x [256][256]
    unsigned short* W2t  = W1t + (size_t)32 * 65536;
    unsigned short* W3t  = W2t + (size_t)32 * 65536;         // 32 nets x [32][256]
    unsigned short* Wm   = W3t + (size_t)32 * 8192;          // 8 slots x 65536

    (void)hipMemsetAsync(out, 0, Bc * sizeof(float), stream);

    // prep (single launch: transposes + X conversion; 64 conv slices)
    prep_all_kernel<<<dim3(8, 8, 168), 256, 0, stream>>>(
        kW1, vW1, kW2, vW2, kW3, vW3,
        ds_W, ff_W1, ff_W2, de_W1, de_W2, de_W3, encoded,
        W1t, W2t, W3t, Wm, Xbf);

    // KV MLPs v7b: 16 rg x 16 (l,h) x {k,v}
    kv_mfma_kernel<<<dim3(16, 16, 2), 512, 0, stream>>>(
        Xbf, true_u, W1t, W2t, W3t, kW1, vW1,
        kb1, kb2, kb3, vb1, vb2, vb3, keys, vals);

    // fused tail: 256 blocks x 16 rows (V-preload attention)
    decoder_kernel<<<dim3(ROWS_AT / 16), 512, 0, stream>>>(
        Xbf, true_u, keys, vals, neighbor_index, attn_mask, pred_points, Wm,
        ds_b, ln1_g, ln1_b, ff_b1, ff_b2, ln2_g, ln2_b,
        de_b1, de_b2, de_b3, out);
}